// Round 8
// baseline (796.075 us; speedup 1.0000x reference)
//
#include <hip/hip_runtime.h>
#include <hip/hip_bf16.h>
#include <cstdint>

#define B_  4
#define LQ_ 2048
#define LK_ 2048
#define D_  1024
#define H_  16
#define HD_ 64

typedef __attribute__((ext_vector_type(8))) short bf16x8;   // 8 bf16 in 4 VGPRs
typedef __attribute__((ext_vector_type(4))) float f32x4;    // MFMA C/D

#if defined(__has_builtin)
#if __has_builtin(__builtin_amdgcn_exp2f)
#define EXP2F(x) __builtin_amdgcn_exp2f(x)
#else
#define EXP2F(x) exp2f(x)
#endif
#else
#define EXP2F(x) exp2f(x)
#endif

__device__ __forceinline__ unsigned short f2b(float f) {   // RNE
    union { float f; unsigned u; } v; v.f = f;
    unsigned u = v.u;
    unsigned r = (u + 0x7fffu + ((u >> 16) & 1u)) >> 16;
    return (unsigned short)r;
}

// async global->LDS, 16B per lane. LDS dest: wave-uniform base + lane*16.
__device__ __forceinline__ void gl_lds16(const unsigned short* g, unsigned short* l) {
    __builtin_amdgcn_global_load_lds(
        (const __attribute__((address_space(1))) unsigned int*)(g),
        (__attribute__((address_space(3))) unsigned int*)(l),
        16, 0, 0);
}

#define PHASE_BARRIER() do { \
    __builtin_amdgcn_sched_barrier(0); \
    __builtin_amdgcn_s_barrier(); \
    __builtin_amdgcn_sched_barrier(0); } while (0)

#define WAITVM(N) do { \
    asm volatile("s_waitcnt vmcnt(" #N ")" ::: "memory"); \
    __builtin_amdgcn_sched_barrier(0); } while (0)

#define WAITLGKM0() do { \
    asm volatile("s_waitcnt lgkmcnt(0)" ::: "memory"); \
    __builtin_amdgcn_sched_barrier(0); } while (0)

// ---------------------------------------------------------------------------
// Fused fp32->bf16 for all 5 tensors; blockIdx.y selects. Wq scaled by s0.
// (round-6 config restored: grid (4096,5) — r7's grid-stride variant cost
// ~7us of non-attn time.)
// ---------------------------------------------------------------------------
__global__ void cvt_all(const float* __restrict__ a0, unsigned short* __restrict__ d0,
                        const float* __restrict__ a1, unsigned short* __restrict__ d1,
                        const float* __restrict__ w0, unsigned short* __restrict__ e0, float s0,
                        const float* __restrict__ w1, unsigned short* __restrict__ e1,
                        const float* __restrict__ w2, unsigned short* __restrict__ e2,
                        int nact, int nw) {
    const float* in; unsigned short* out; float s = 1.0f; int n;
    switch (blockIdx.y) {
        case 0: in = a0; out = d0; n = nact; break;
        case 1: in = a1; out = d1; n = nact; break;
        case 2: in = w0; out = e0; n = nw; s = s0; break;
        case 3: in = w1; out = e1; n = nw; break;
        default: in = w2; out = e2; n = nw; break;
    }
    int i = (blockIdx.x * blockDim.x + threadIdx.x) * 8;
    int stride = gridDim.x * blockDim.x * 8;
    for (; i < n; i += stride) {
        float4 x = *(const float4*)(in + i);
        float4 y = *(const float4*)(in + i + 4);
        bf16x8 v;
        v[0] = (short)f2b(x.x * s); v[1] = (short)f2b(x.y * s);
        v[2] = (short)f2b(x.z * s); v[3] = (short)f2b(x.w * s);
        v[4] = (short)f2b(y.x * s); v[5] = (short)f2b(y.y * s);
        v[6] = (short)f2b(y.z * s); v[7] = (short)f2b(y.w * s);
        *(bf16x8*)(out + i) = v;
    }
}

// ---------------------------------------------------------------------------
// Fused QKV projection GEMM v3 — 256x256 tile, BK=64, 8 waves, SAME 16-MFMA
// phase density as round-1, but LDS ring shrunk 4 slots -> 2 (E/O parity):
// 128KB -> 64KB => 2 blocks/CU => all 384 blocks CO-RESIDENT (was 1.5
// dispatch rounds at 1 block/CU = <=75% CU-time). Hazard-checked schedule:
//   top: WAITVM(4) [drain E(t), O(t) stays in flight] + barrier
//   P1 : ds_read all 12 E-frags; 16 MFMA (nf 0,1)
//   P2 : lgkmcnt(0)+barrier [all waves' E-reads in regs]; 16 MFMA (nf 2,3);
//        stage E(t+1)
//   P3 : WAITVM(4) [drain O(t), E(t+1) in flight] + barrier; ds_read O;
//        16 MFMA (nf 0,1)
//   P4 : lgkmcnt(0)+barrier; 16 MFMA (nf 2,3); stage O(t+1)
// vmcnt never 0 mid-stream; every stage has a ~2-phase landing window.
// ---------------------------------------------------------------------------
__global__ __launch_bounds__(512, 4) void qkv_gemm(
    const unsigned short* __restrict__ Xq,
    const unsigned short* __restrict__ Xkv,
    const unsigned short* __restrict__ Wqb, const unsigned short* __restrict__ Wkb,
    const unsigned short* __restrict__ Wvb,
    const float* __restrict__ bq, const float* __restrict__ bk,
    const float* __restrict__ bv, float qscale,
    unsigned short* __restrict__ Qb, unsigned short* __restrict__ Kb,
    unsigned short* __restrict__ Vtb)
{
    __shared__ unsigned short AS[2][8192];   // slot 0=E(kh0), 1=O(kh1): 16 frags x 512
    __shared__ unsigned short BS[2][8192];

    const int proj = blockIdx.y >> 2;
    const int nt0  = blockIdx.y & 3;
    const unsigned short* X = (proj == 0) ? Xq : Xkv;
    const unsigned short* W = (proj == 0) ? Wqb : (proj == 1 ? Wkb : Wvb);
    const float* bias       = (proj == 0) ? bq  : (proj == 1 ? bk  : bv);
    const float bscale      = (proj == 0) ? qscale : 1.0f;

    const int tid  = threadIdx.x;
    const int lane = tid & 63;
    const int w    = tid >> 6;                 // 0..7
    const int wm   = w & 1, wn = w >> 1;       // 2M x 4N wave grid
    const int m0   = blockIdx.x * 256;
    const int n0   = nt0 * 256;
    const int l15  = lane & 15, quad = lane >> 4;

    f32x4 acc[8][4] = {};

    // staging sources: wave w stages frags w*2, w*2+1 of each 16-frag half
    const unsigned short* gA0 = X + (size_t)(m0 + (w * 2) * 16 + l15) * 1024 + quad * 8;
    const unsigned short* gA1 = gA0 + 16 * 1024;
    const unsigned short* gB0 = W + (size_t)(n0 + (w * 2) * 16 + l15) * 1024 + quad * 8;
    const unsigned short* gB1 = gB0 + 16 * 1024;

#define STAGE_A(slot, koff) do { \
    gl_lds16(gA0 + (koff), &AS[slot][(w * 2) * 512 + lane * 8]); \
    gl_lds16(gA1 + (koff), &AS[slot][(w * 2 + 1) * 512 + lane * 8]); } while (0)
#define STAGE_B(slot, koff) do { \
    gl_lds16(gB0 + (koff), &BS[slot][(w * 2) * 512 + lane * 8]); \
    gl_lds16(gB1 + (koff), &BS[slot][(w * 2 + 1) * 512 + lane * 8]); } while (0)

    const int aoff = (wm * 8) * 512 + lane * 8;   // my 8 m-frags
    const int boff = (wn * 4) * 512 + lane * 8;   // my 4 n-frags

    // prologue: E(0) then O(0) — queue (oldest first): [E0:4, O0:4]
    STAGE_A(0, 0);   STAGE_B(0, 0);
    STAGE_A(1, 32);  STAGE_B(1, 32);

    for (int t = 0; t < 16; ++t) {
        const int ke = t * 64;

        // ---- top: E(t) landed (O(t) stays in flight) ----
        WAITVM(4);
        PHASE_BARRIER();

        bf16x8 af[8], b0, b1, b2, b3;

        // ---- P1: read ALL E frags, MFMA nf 0,1 ----
        #pragma unroll
        for (int i = 0; i < 8; ++i)
            af[i] = *(const bf16x8*)(&AS[0][aoff + i * 512]);
        b0 = *(const bf16x8*)(&BS[0][boff]);
        b1 = *(const bf16x8*)(&BS[0][boff + 512]);
        b2 = *(const bf16x8*)(&BS[0][boff + 1024]);
        b3 = *(const bf16x8*)(&BS[0][boff + 1536]);
        __builtin_amdgcn_s_setprio(1);
        #pragma unroll
        for (int i = 0; i < 8; ++i) {
            acc[i][0] = __builtin_amdgcn_mfma_f32_16x16x32_bf16(af[i], b0, acc[i][0], 0, 0, 0);
            acc[i][1] = __builtin_amdgcn_mfma_f32_16x16x32_bf16(af[i], b1, acc[i][1], 0, 0, 0);
        }
        __builtin_amdgcn_s_setprio(0);

        // ---- P2: all waves' E-reads secured, MFMA nf 2,3, stage E(t+1) ----
        WAITLGKM0();
        PHASE_BARRIER();
        __builtin_amdgcn_s_setprio(1);
        #pragma unroll
        for (int i = 0; i < 8; ++i) {
            acc[i][2] = __builtin_amdgcn_mfma_f32_16x16x32_bf16(af[i], b2, acc[i][2], 0, 0, 0);
            acc[i][3] = __builtin_amdgcn_mfma_f32_16x16x32_bf16(af[i], b3, acc[i][3], 0, 0, 0);
        }
        __builtin_amdgcn_s_setprio(0);
        if (t < 15) { STAGE_A(0, ke + 64); STAGE_B(0, ke + 64); }

        // ---- P3: O(t) landed (E(t+1) stays in flight); read O, MFMA ----
        if (t < 15) { WAITVM(4); } else { WAITVM(0); }
        PHASE_BARRIER();
        #pragma unroll
        for (int i = 0; i < 8; ++i)
            af[i] = *(const bf16x8*)(&AS[1][aoff + i * 512]);
        b0 = *(const bf16x8*)(&BS[1][boff]);
        b1 = *(const bf16x8*)(&BS[1][boff + 512]);
        b2 = *(const bf16x8*)(&BS[1][boff + 1024]);
        b3 = *(const bf16x8*)(&BS[1][boff + 1536]);
        __builtin_amdgcn_s_setprio(1);
        #pragma unroll
        for (int i = 0; i < 8; ++i) {
            acc[i][0] = __builtin_amdgcn_mfma_f32_16x16x32_bf16(af[i], b0, acc[i][0], 0, 0, 0);
            acc[i][1] = __builtin_amdgcn_mfma_f32_16x16x32_bf16(af[i], b1, acc[i][1], 0, 0, 0);
        }
        __builtin_amdgcn_s_setprio(0);

        // ---- P4: MFMA nf 2,3, stage O(t+1) ----
        WAITLGKM0();
        PHASE_BARRIER();
        __builtin_amdgcn_s_setprio(1);
        #pragma unroll
        for (int i = 0; i < 8; ++i) {
            acc[i][2] = __builtin_amdgcn_mfma_f32_16x16x32_bf16(af[i], b2, acc[i][2], 0, 0, 0);
            acc[i][3] = __builtin_amdgcn_mfma_f32_16x16x32_bf16(af[i], b3, acc[i][3], 0, 0, 0);
        }
        __builtin_amdgcn_s_setprio(0);
        if (t < 15) { STAGE_A(1, ke + 96); STAGE_B(1, ke + 96); }
    }

#undef STAGE_A
#undef STAGE_B

    float bvv[4];
    #pragma unroll
    for (int j = 0; j < 4; ++j)
        bvv[j] = bias[n0 + wn * 64 + j * 16 + l15] * bscale;

    if (proj == 2) {
        // ---- transposed epilogue: write Vt[(b*1024+col)*2048 + tok] ----
        #pragma unroll
        for (int i = 0; i < 8; ++i) {
            int row = m0 + wm * 128 + i * 16 + quad * 4;   // token base (r=0..3)
            int bb  = row >> 11;
            int tt  = row & 2047;
            #pragma unroll
            for (int j = 0; j < 4; ++j) {
                int col = n0 + wn * 64 + j * 16 + l15;
                unsigned s0v = f2b(acc[i][j][0] + bvv[j]);
                unsigned s1v = f2b(acc[i][j][1] + bvv[j]);
                unsigned s2v = f2b(acc[i][j][2] + bvv[j]);
                unsigned s3v = f2b(acc[i][j][3] + bvv[j]);
                uint2 pk;
                pk.x = s0v | (s1v << 16);
                pk.y = s2v | (s3v << 16);
                *(uint2*)(Vtb + ((size_t)(bb * 1024 + col)) * 2048 + tt) = pk;
            }
        }
    } else {
        unsigned short* Y = (proj == 0) ? Qb : Kb;
        #pragma unroll
        for (int i = 0; i < 8; ++i) {
            #pragma unroll
            for (int r = 0; r < 4; ++r) {
                int row = m0 + wm * 128 + i * 16 + quad * 4 + r;
                unsigned short* yp = Y + (size_t)row * 1024 + n0 + wn * 64;
                #pragma unroll
                for (int j = 0; j < 4; ++j)
                    yp[j * 16 + l15] = f2b(acc[i][j][r] + bvv[j]);
            }
        }
    }
}

// ---------------------------------------------------------------------------
// Flash attention v8 (round-6 measured 97.2us — restored after v10's
// K->register attempt spilled at the 128-VGPR cap and regressed to 119.8):
// shared LDS staging of K and V + XCD swizzle + K double-buffer, counted
// waits. LDS: K dbuf 32K + Vs 16K + Ps 32K = 80KB -> 2 blocks/CU.
// ---------------------------------------------------------------------------
__global__ __launch_bounds__(256, 2) void attn_kernel(
    const unsigned short* __restrict__ Q,
    const unsigned short* __restrict__ Kp,
    const unsigned short* __restrict__ Vt,
    float* __restrict__ Out)
{
    __shared__ unsigned short Ks[2][16 * 512]; // frag f=kt*2+dblk: K[kt*16+l15][dblk*32+quad*8+j]
    __shared__ unsigned short Vs[16 * 512];    // frag f=nt*4+hb:  V^T[nt*16+l15][hb*32+quad*8+j]
    __shared__ unsigned short Ps[4][4096];     // per-wave, per-half 1024: P[16q][64k] frag-ordered

    const int tid  = threadIdx.x;
    const int lane = tid & 63;
    const int w    = tid >> 6;
    const int l15  = lane & 15, quad = lane >> 4;

    // XCD swizzle: all 8 q-tiles of a (b,h) group share bid%8 -> same XCD,
    // K/V stay L2-resident (proven r2: FETCH 141MB -> 25MB).
    const int bid = blockIdx.x + (blockIdx.y << 3) + (blockIdx.z << 7);
    const int glo = bid & 7;
    const int jx  = bid >> 3;          // 0..63
    const int qt  = jx & 7;
    const int g   = glo + ((jx >> 3) << 3);   // 0..63: (b,h) group
    const int h   = g & 15;
    const int b   = g >> 4;

    bf16x8 qf[4][2];
    #pragma unroll
    for (int half = 0; half < 4; ++half) {
        const unsigned short* qptr =
            Q + (size_t)(b * LQ_ + qt * 256 + w * 64 + half * 16 + l15) * 1024 + h * 64;
        qf[half][0] = *(const bf16x8*)(qptr + quad * 8);
        qf[half][1] = *(const bf16x8*)(qptr + 32 + quad * 8);
    }

    bf16x8 ones;
    #pragma unroll
    for (int j = 0; j < 8; ++j) ones[j] = (short)0x3F80;   // bf16 1.0

    f32x4 oacc[4][4] = {};
    f32x4 lacc[4]    = {};

    const unsigned short* Kbase = Kp + (size_t)b * LK_ * 1024 + h * 64;
    const unsigned short* Vbase = Vt + (size_t)(b * 16 + h) * 64 * 2048;

    const unsigned short* gK[4];
    unsigned short* lK[4];                    // buffer-0 LDS dests
    const unsigned short* gV[4];
    unsigned short* lV[4];
    #pragma unroll
    for (int j = 0; j < 4; ++j) {
        int kt = w + (j >> 1) * 4, dblk = j & 1;
        gK[j] = Kbase + (size_t)(kt * 16 + l15) * 1024 + dblk * 32 + quad * 8;
        lK[j] = &Ks[0][(kt * 2 + dblk) * 512 + lane * 8];
        gV[j] = Vbase + (size_t)(w * 16 + l15) * 2048 + j * 32 + quad * 8;
        lV[j] = &Vs[(w * 4 + j) * 512 + lane * 8];
    }

    // P region: element (q,k) at half*1024 + (k>>3)*128 + q*8 + (k&7)
    const int pws = (quad >> 1) * 128 + l15 * 8 + (quad & 1) * 4;
    unsigned short* PwB = &Ps[w][pws];            // + half*1024 + ti*256
    const unsigned short* PrB = &Ps[w][lane * 8]; // + half*1024 + hbl*512
    const unsigned short* KfrB = &Ks[0][lane * 8];
    const unsigned short* Vfr = &Vs[lane * 8];

    // prologue: stage K(0) into buffer 0
    #pragma unroll
    for (int j = 0; j < 4; ++j) gl_lds16(gK[j], lK[j]);

    for (int t = 0; t < 16; ++t) {
        const int cur = t & 1;
        const int k0 = t * 128;

        // stage V(t); prefetch K(t+1) into other buffer
        #pragma unroll
        for (int j = 0; j < 4; ++j) gl_lds16(gV[j] + k0, lV[j]);
        if (t < 15) {
            const int stoff = (cur ^ 1) * 8192;
            #pragma unroll
            for (int j = 0; j < 4; ++j)
                gl_lds16(gK[j] + (size_t)(t + 1) * (128 * 1024), lK[j] + stoff);
        }
        if (t == 0) {          // K(0) landed (V(0)+K(1) = 8 still in flight)
            WAITVM(8);
            PHASE_BARRIER();
        }
        const unsigned short* Kfr = KfrB + cur * 8192;

        #pragma unroll
        for (int cc = 0; cc < 2; ++cc) {          // two 64-key chunks
            // ---- QK^T, all 4 halves share each kf read ----
            f32x4 st[4][4] = {};
            #pragma unroll
            for (int ti = 0; ti < 4; ++ti)
                #pragma unroll
                for (int dblk = 0; dblk < 2; ++dblk) {
                    bf16x8 kf = *(const bf16x8*)(Kfr + ((cc * 4 + ti) * 2 + dblk) * 512);
                    #pragma unroll
                    for (int half = 0; half < 4; ++half)
                        st[half][ti] = __builtin_amdgcn_mfma_f32_16x16x32_bf16(
                            kf, qf[half][dblk], st[half][ti], 0, 0, 0);
                }

            // ---- p = exp2(s); pack (RHU) into per-half P regions ----
            #pragma unroll
            for (int half = 0; half < 4; ++half) {
                unsigned short* pw = PwB + half * 1024;
                #pragma unroll
                for (int ti = 0; ti < 4; ++ti) {
                    unsigned u0 = __float_as_uint(EXP2F(st[half][ti][0])) + 0x8000u;
                    unsigned u1 = __float_as_uint(EXP2F(st[half][ti][1])) + 0x8000u;
                    unsigned u2 = __float_as_uint(EXP2F(st[half][ti][2])) + 0x8000u;
                    unsigned u3 = __float_as_uint(EXP2F(st[half][ti][3])) + 0x8000u;
                    uint2 pk;
                    pk.x = __builtin_amdgcn_perm(u1, u0, 0x07060302);
                    pk.y = __builtin_amdgcn_perm(u3, u2, 0x07060302);
                    *(uint2*)(pw + ti * 256) = pk;
                }
            }

            // ---- after chunk0's compute has covered V latency: V ready ----
            if (cc == 0) {
                if (t < 15) { WAITVM(4); } else { WAITVM(0); }
                PHASE_BARRIER();      // Vs visible to all waves
            }

            // ---- PV + ones row-sum; vf read once per (nt,hbl), shared ----
            #pragma unroll
            for (int hbl = 0; hbl < 2; ++hbl) {
                bf16x8 pf[4];
                #pragma unroll
                for (int half = 0; half < 4; ++half) {
                    pf[half] = *(const bf16x8*)(PrB + half * 1024 + hbl * 512);
                    lacc[half] = __builtin_amdgcn_mfma_f32_16x16x32_bf16(
                        pf[half], ones, lacc[half], 0, 0, 0);
                }
                int hb = cc * 2 + hbl;
                #pragma unroll
                for (int nt = 0; nt < 4; ++nt) {
                    bf16x8 vf = *(const bf16x8*)(Vfr + (nt * 4 + hb) * 512);
                    #pragma unroll
                    for (int half = 0; half < 4; ++half)
                        oacc[half][nt] = __builtin_amdgcn_mfma_f32_16x16x32_bf16(
                            pf[half], vf, oacc[half][nt], 0, 0, 0);
                }
            }
        }

        if (t < 15) {
            WAITVM(0);        // K(t+1): issued a full tile of MFMA ago — free
            PHASE_BARRIER();  // K visible; Vs safe to overwrite next tile
        }
    }

    // ---- normalize + store ----
    #pragma unroll
    for (int half = 0; half < 4; ++half) {
        float il[4];
        #pragma unroll
        for (int r = 0; r < 4; ++r) il[r] = 1.0f / lacc[half][r];
        #pragma unroll
        for (int nt = 0; nt < 4; ++nt) {
            #pragma unroll
            for (int r = 0; r < 4; ++r) {
                size_t orow = (size_t)(b * LQ_ + qt * 256 + w * 64 + half * 16 + quad * 4 + r);
                Out[orow * 1024 + h * 64 + nt * 16 + l15] = oacc[half][nt][r] * il[r];
            }
        }
    }
}

// ---------------------------------------------------------------------------
extern "C" void kernel_launch(void* const* d_in, const int* in_sizes, int n_in,
                              void* d_out, int out_size, void* d_ws, size_t ws_size,
                              hipStream_t stream) {
    const float* zt = (const float*)d_in[0];
    const float* ic = (const float*)d_in[1];
    const float* Wq = (const float*)d_in[2];
    const float* bq = (const float*)d_in[3];
    const float* Wk = (const float*)d_in[4];
    const float* bk = (const float*)d_in[5];
    const float* Wv = (const float*)d_in[6];
    const float* bv = (const float*)d_in[7];
    float* out = (float*)d_out;

    const size_t M8 = (size_t)8192 * 1024;
    const size_t M1 = (size_t)1024 * 1024;
    unsigned short* Qb  = (unsigned short*)d_ws;
    unsigned short* Kb  = Qb  + M8;
    unsigned short* Vtb = Kb  + M8;          // V written transposed by qkv_gemm
    unsigned short* Xz  = Vtb + M8;
    unsigned short* Xi  = Xz  + M8;
    unsigned short* Wqb = Xi  + M8;
    unsigned short* Wkb = Wqb + M1;
    unsigned short* Wvb = Wkb + M1;

    const float qscale = 0.125f * 1.44269504088896f;  // 1/sqrt(64) * log2(e)

    dim3 gcv(4096, 5);
    cvt_all<<<gcv, 256, 0, stream>>>(zt, Xz, ic, Xi,
                                     Wq, Wqb, qscale, Wk, Wkb, Wv, Wvb,
                                     (int)M8, (int)M1);

    dim3 gproj(32, 12);                      // m-tile (8192/256), proj*4 + n-tile
    qkv_gemm<<<gproj, 512, 0, stream>>>(Xz, Xi, Wqb, Wkb, Wvb,
                                        bq, bk, bv, qscale, Qb, Kb, Vtb);

    dim3 gattn(8, 16, 4);                    // flattened+swizzled inside kernel
    attn_kernel<<<gattn, 256, 0, stream>>>(Qb, Kb, Vtb, out);
}

// Round 9
// 296.864 us; speedup vs baseline: 2.6816x; 2.6816x over previous
//
#include <hip/hip_runtime.h>
#include <hip/hip_bf16.h>
#include <cstdint>

#define B_  4
#define LQ_ 2048
#define LK_ 2048
#define D_  1024
#define H_  16
#define HD_ 64

typedef __attribute__((ext_vector_type(8))) short bf16x8;   // 8 bf16 in 4 VGPRs
typedef __attribute__((ext_vector_type(4))) float f32x4;    // MFMA C/D

#if defined(__has_builtin)
#if __has_builtin(__builtin_amdgcn_exp2f)
#define EXP2F(x) __builtin_amdgcn_exp2f(x)
#else
#define EXP2F(x) exp2f(x)
#endif
#else
#define EXP2F(x) exp2f(x)
#endif

__device__ __forceinline__ unsigned short f2b(float f) {   // RNE
    union { float f; unsigned u; } v; v.f = f;
    unsigned u = v.u;
    unsigned r = (u + 0x7fffu + ((u >> 16) & 1u)) >> 16;
    return (unsigned short)r;
}

// async global->LDS, 16B per lane. LDS dest: wave-uniform base + lane*16.
__device__ __forceinline__ void gl_lds16(const unsigned short* g, unsigned short* l) {
    __builtin_amdgcn_global_load_lds(
        (const __attribute__((address_space(1))) unsigned int*)(g),
        (__attribute__((address_space(3))) unsigned int*)(l),
        16, 0, 0);
}

#define PHASE_BARRIER() do { \
    __builtin_amdgcn_sched_barrier(0); \
    __builtin_amdgcn_s_barrier(); \
    __builtin_amdgcn_sched_barrier(0); } while (0)

#define WAITVM(N) do { \
    asm volatile("s_waitcnt vmcnt(" #N ")" ::: "memory"); \
    __builtin_amdgcn_sched_barrier(0); } while (0)

// ---------------------------------------------------------------------------
// Fused fp32->bf16 for all 5 tensors; blockIdx.y selects. Wq scaled by s0.
// (round-6 config: grid (4096,5), one-shot blocks.)
// ---------------------------------------------------------------------------
__global__ void cvt_all(const float* __restrict__ a0, unsigned short* __restrict__ d0,
                        const float* __restrict__ a1, unsigned short* __restrict__ d1,
                        const float* __restrict__ w0, unsigned short* __restrict__ e0, float s0,
                        const float* __restrict__ w1, unsigned short* __restrict__ e1,
                        const float* __restrict__ w2, unsigned short* __restrict__ e2,
                        int nact, int nw) {
    const float* in; unsigned short* out; float s = 1.0f; int n;
    switch (blockIdx.y) {
        case 0: in = a0; out = d0; n = nact; break;
        case 1: in = a1; out = d1; n = nact; break;
        case 2: in = w0; out = e0; n = nw; s = s0; break;
        case 3: in = w1; out = e1; n = nw; break;
        default: in = w2; out = e2; n = nw; break;
    }
    int i = (blockIdx.x * blockDim.x + threadIdx.x) * 8;
    int stride = gridDim.x * blockDim.x * 8;
    for (; i < n; i += stride) {
        float4 x = *(const float4*)(in + i);
        float4 y = *(const float4*)(in + i + 4);
        bf16x8 v;
        v[0] = (short)f2b(x.x * s); v[1] = (short)f2b(x.y * s);
        v[2] = (short)f2b(x.z * s); v[3] = (short)f2b(x.w * s);
        v[4] = (short)f2b(y.x * s); v[5] = (short)f2b(y.y * s);
        v[6] = (short)f2b(y.z * s); v[7] = (short)f2b(y.w * s);
        *(bf16x8*)(out + i) = v;
    }
}

// ---------------------------------------------------------------------------
// Fused QKV projection GEMM — round-1 schedule (proven ~91us), 256x256 tile,
// BK=64, 8 waves (2M x 4N), 4-phase counted-vmcnt (T3+T4+T5), 4-slot
// half-tile LDS ring (128KB), __launch_bounds__(512,2) (VGPR cap 256 —
// r8 lesson: this tile needs 128 AGPR + ~90 VGPR; (512,4)'s 64/64 split
// spilled catastrophically; 256^2 is structurally 1 block/CU).
// NEW (round 9): T1 XCD swizzle — flat grid 384 (384%8==0, bijective):
// XCD (bid&7) owns m-tiles 4*xcd..4*xcd+3, so the 12 blocks sharing an
// X m-panel (512KB) land on ONE XCD's L2 (r2/r4: FETCH 141->~50MB on this
// workload), turning staging waits from HBM (~900cy) into L2 (~200cy) hits.
// Round-6 transposed V epilogue kept.
// ---------------------------------------------------------------------------
__global__ __launch_bounds__(512, 2) void qkv_gemm(
    const unsigned short* __restrict__ Xq,
    const unsigned short* __restrict__ Xkv,
    const unsigned short* __restrict__ Wqb, const unsigned short* __restrict__ Wkb,
    const unsigned short* __restrict__ Wvb,
    const float* __restrict__ bq, const float* __restrict__ bk,
    const float* __restrict__ bv, float qscale,
    unsigned short* __restrict__ Qb, unsigned short* __restrict__ Kb,
    unsigned short* __restrict__ Vtb)
{
    __shared__ unsigned short AS[4][8192];   // slot (2t+kh)&3 : 16 frags x 512
    __shared__ unsigned short BS[4][8192];

    // XCD swizzle: bid = xcd + 8*j ; mt = xcd*4 + (j&3) ; yy = j>>2.
    const int bid  = blockIdx.x;
    const int xcd  = bid & 7;
    const int jj   = bid >> 3;           // 0..47
    const int mt   = xcd * 4 + (jj & 3); // 0..31
    const int yy   = jj >> 2;            // 0..11
    const int proj = yy >> 2;
    const int nt0  = yy & 3;

    const unsigned short* X = (proj == 0) ? Xq : Xkv;
    const unsigned short* W = (proj == 0) ? Wqb : (proj == 1 ? Wkb : Wvb);
    const float* bias       = (proj == 0) ? bq  : (proj == 1 ? bk  : bv);
    const float bscale      = (proj == 0) ? qscale : 1.0f;

    const int tid  = threadIdx.x;
    const int lane = tid & 63;
    const int w    = tid >> 6;                 // 0..7
    const int wm   = w & 1, wn = w >> 1;       // 2M x 4N wave grid
    const int m0   = mt * 256;
    const int n0   = nt0 * 256;
    const int l15  = lane & 15, quad = lane >> 4;

    f32x4 acc[8][4] = {};

    // staging sources: wave w stages frags w*2, w*2+1 of each 16-frag half
    const unsigned short* gA0 = X + (size_t)(m0 + (w * 2) * 16 + l15) * 1024 + quad * 8;
    const unsigned short* gA1 = gA0 + 16 * 1024;
    const unsigned short* gB0 = W + (size_t)(n0 + (w * 2) * 16 + l15) * 1024 + quad * 8;
    const unsigned short* gB1 = gB0 + 16 * 1024;

#define STAGE_A(slot, koff) do { \
    gl_lds16(gA0 + (koff), &AS[slot][(w * 2) * 512 + lane * 8]); \
    gl_lds16(gA1 + (koff), &AS[slot][(w * 2 + 1) * 512 + lane * 8]); } while (0)
#define STAGE_B(slot, koff) do { \
    gl_lds16(gB0 + (koff), &BS[slot][(w * 2) * 512 + lane * 8]); \
    gl_lds16(gB1 + (koff), &BS[slot][(w * 2 + 1) * 512 + lane * 8]); } while (0)

    const int aoff = (wm * 8) * 512 + lane * 8;   // my 8 m-frags
    const int boff = (wn * 4) * 512 + lane * 8;   // my 4 n-frags

    // prologue: tiles 0 (both halves) + tile 1 kh0, in ring-issue order
    STAGE_A(0, 0);   STAGE_B(0, 0);
    STAGE_A(1, 32);  STAGE_B(1, 32);
    STAGE_A(2, 64);  STAGE_B(2, 64);
    WAITVM(8);
    __builtin_amdgcn_s_barrier();
    __builtin_amdgcn_sched_barrier(0);

    #pragma unroll 2
    for (int t = 0; t < 16; ++t) {
        const int s0 = (2 * t) & 3;
        const int s1 = (2 * t + 1) & 3;
        const int s3 = (2 * t + 3) & 3;

        bf16x8 af[8], bf0, bf1;

        // ---- P1: kh0, n-frags 0,1 ----
        #pragma unroll
        for (int i = 0; i < 8; ++i)
            af[i] = *(const bf16x8*)(&AS[s0][aoff + i * 512]);
        bf0 = *(const bf16x8*)(&BS[s0][boff]);
        bf1 = *(const bf16x8*)(&BS[s0][boff + 512]);
        PHASE_BARRIER();
        __builtin_amdgcn_s_setprio(1);
        #pragma unroll
        for (int i = 0; i < 8; ++i) {
            acc[i][0] = __builtin_amdgcn_mfma_f32_16x16x32_bf16(af[i], bf0, acc[i][0], 0, 0, 0);
            acc[i][1] = __builtin_amdgcn_mfma_f32_16x16x32_bf16(af[i], bf1, acc[i][1], 0, 0, 0);
        }
        __builtin_amdgcn_s_setprio(0);
        if (t < 15) STAGE_A(s3, (t + 1) * 64 + 32);

        // ---- P2: kh0, n-frags 2,3 (af reused) ----
        bf0 = *(const bf16x8*)(&BS[s0][boff + 1024]);
        bf1 = *(const bf16x8*)(&BS[s0][boff + 1536]);
        if (t < 14) { WAITVM(6); } else { WAITVM(0); }
        PHASE_BARRIER();
        __builtin_amdgcn_s_setprio(1);
        #pragma unroll
        for (int i = 0; i < 8; ++i) {
            acc[i][2] = __builtin_amdgcn_mfma_f32_16x16x32_bf16(af[i], bf0, acc[i][2], 0, 0, 0);
            acc[i][3] = __builtin_amdgcn_mfma_f32_16x16x32_bf16(af[i], bf1, acc[i][3], 0, 0, 0);
        }
        __builtin_amdgcn_s_setprio(0);
        if (t < 15) STAGE_B(s3, (t + 1) * 64 + 32);

        // ---- P3: kh1, n-frags 0,1 ----
        #pragma unroll
        for (int i = 0; i < 8; ++i)
            af[i] = *(const bf16x8*)(&AS[s1][aoff + i * 512]);
        bf0 = *(const bf16x8*)(&BS[s1][boff]);
        bf1 = *(const bf16x8*)(&BS[s1][boff + 512]);
        PHASE_BARRIER();
        __builtin_amdgcn_s_setprio(1);
        #pragma unroll
        for (int i = 0; i < 8; ++i) {
            acc[i][0] = __builtin_amdgcn_mfma_f32_16x16x32_bf16(af[i], bf0, acc[i][0], 0, 0, 0);
            acc[i][1] = __builtin_amdgcn_mfma_f32_16x16x32_bf16(af[i], bf1, acc[i][1], 0, 0, 0);
        }
        __builtin_amdgcn_s_setprio(0);
        if (t < 14) STAGE_A(s0, (t + 2) * 64);

        // ---- P4: kh1, n-frags 2,3 ----
        bf0 = *(const bf16x8*)(&BS[s1][boff + 1024]);
        bf1 = *(const bf16x8*)(&BS[s1][boff + 1536]);
        if (t < 14) { WAITVM(6); } else if (t == 14) { WAITVM(4); }
        PHASE_BARRIER();
        __builtin_amdgcn_s_setprio(1);
        #pragma unroll
        for (int i = 0; i < 8; ++i) {
            acc[i][2] = __builtin_amdgcn_mfma_f32_16x16x32_bf16(af[i], bf0, acc[i][2], 0, 0, 0);
            acc[i][3] = __builtin_amdgcn_mfma_f32_16x16x32_bf16(af[i], bf1, acc[i][3], 0, 0, 0);
        }
        __builtin_amdgcn_s_setprio(0);
        if (t < 14) STAGE_B(s0, (t + 2) * 64);
    }

#undef STAGE_A
#undef STAGE_B

    float bvv[4];
    #pragma unroll
    for (int j = 0; j < 4; ++j)
        bvv[j] = bias[n0 + wn * 64 + j * 16 + l15] * bscale;

    if (proj == 2) {
        // ---- transposed epilogue: write Vt[(b*1024+col)*2048 + tok] ----
        #pragma unroll
        for (int i = 0; i < 8; ++i) {
            int row = m0 + wm * 128 + i * 16 + quad * 4;   // token base (r=0..3)
            int bb  = row >> 11;
            int tt  = row & 2047;
            #pragma unroll
            for (int j = 0; j < 4; ++j) {
                int col = n0 + wn * 64 + j * 16 + l15;
                unsigned s0v = f2b(acc[i][j][0] + bvv[j]);
                unsigned s1v = f2b(acc[i][j][1] + bvv[j]);
                unsigned s2v = f2b(acc[i][j][2] + bvv[j]);
                unsigned s3v = f2b(acc[i][j][3] + bvv[j]);
                uint2 pk;
                pk.x = s0v | (s1v << 16);
                pk.y = s2v | (s3v << 16);
                *(uint2*)(Vtb + ((size_t)(bb * 1024 + col)) * 2048 + tt) = pk;
            }
        }
    } else {
        unsigned short* Y = (proj == 0) ? Qb : Kb;
        #pragma unroll
        for (int i = 0; i < 8; ++i) {
            #pragma unroll
            for (int r = 0; r < 4; ++r) {
                int row = m0 + wm * 128 + i * 16 + quad * 4 + r;
                unsigned short* yp = Y + (size_t)row * 1024 + n0 + wn * 64;
                #pragma unroll
                for (int j = 0; j < 4; ++j)
                    yp[j * 16 + l15] = f2b(acc[i][j][r] + bvv[j]);
            }
        }
    }
}

// ---------------------------------------------------------------------------
// Flash attention v8 (round-6 measured 97.2us, exact): shared LDS staging
// of K and V + XCD swizzle + K double-buffer, counted waits.
// LDS: K dbuf 32K + Vs 16K + Ps 32K = 80KB -> 2 blocks/CU.
// ---------------------------------------------------------------------------
__global__ __launch_bounds__(256, 2) void attn_kernel(
    const unsigned short* __restrict__ Q,
    const unsigned short* __restrict__ Kp,
    const unsigned short* __restrict__ Vt,
    float* __restrict__ Out)
{
    __shared__ unsigned short Ks[2][16 * 512]; // frag f=kt*2+dblk: K[kt*16+l15][dblk*32+quad*8+j]
    __shared__ unsigned short Vs[16 * 512];    // frag f=nt*4+hb:  V^T[nt*16+l15][hb*32+quad*8+j]
    __shared__ unsigned short Ps[4][4096];     // per-wave, per-half 1024: P[16q][64k] frag-ordered

    const int tid  = threadIdx.x;
    const int lane = tid & 63;
    const int w    = tid >> 6;
    const int l15  = lane & 15, quad = lane >> 4;

    // XCD swizzle: all 8 q-tiles of a (b,h) group share bid%8 -> same XCD,
    // K/V stay L2-resident (proven r2: FETCH 141MB -> 25MB).
    const int bid = blockIdx.x + (blockIdx.y << 3) + (blockIdx.z << 7);
    const int glo = bid & 7;
    const int jx  = bid >> 3;          // 0..63
    const int qt  = jx & 7;
    const int g   = glo + ((jx >> 3) << 3);   // 0..63: (b,h) group
    const int h   = g & 15;
    const int b   = g >> 4;

    bf16x8 qf[4][2];
    #pragma unroll
    for (int half = 0; half < 4; ++half) {
        const unsigned short* qptr =
            Q + (size_t)(b * LQ_ + qt * 256 + w * 64 + half * 16 + l15) * 1024 + h * 64;
        qf[half][0] = *(const bf16x8*)(qptr + quad * 8);
        qf[half][1] = *(const bf16x8*)(qptr + 32 + quad * 8);
    }

    bf16x8 ones;
    #pragma unroll
    for (int j = 0; j < 8; ++j) ones[j] = (short)0x3F80;   // bf16 1.0

    f32x4 oacc[4][4] = {};
    f32x4 lacc[4]    = {};

    const unsigned short* Kbase = Kp + (size_t)b * LK_ * 1024 + h * 64;
    const unsigned short* Vbase = Vt + (size_t)(b * 16 + h) * 64 * 2048;

    const unsigned short* gK[4];
    unsigned short* lK[4];                    // buffer-0 LDS dests
    const unsigned short* gV[4];
    unsigned short* lV[4];
    #pragma unroll
    for (int j = 0; j < 4; ++j) {
        int kt = w + (j >> 1) * 4, dblk = j & 1;
        gK[j] = Kbase + (size_t)(kt * 16 + l15) * 1024 + dblk * 32 + quad * 8;
        lK[j] = &Ks[0][(kt * 2 + dblk) * 512 + lane * 8];
        gV[j] = Vbase + (size_t)(w * 16 + l15) * 2048 + j * 32 + quad * 8;
        lV[j] = &Vs[(w * 4 + j) * 512 + lane * 8];
    }

    // P region: element (q,k) at half*1024 + (k>>3)*128 + q*8 + (k&7)
    const int pws = (quad >> 1) * 128 + l15 * 8 + (quad & 1) * 4;
    unsigned short* PwB = &Ps[w][pws];            // + half*1024 + ti*256
    const unsigned short* PrB = &Ps[w][lane * 8]; // + half*1024 + hbl*512
    const unsigned short* KfrB = &Ks[0][lane * 8];
    const unsigned short* Vfr = &Vs[lane * 8];

    // prologue: stage K(0) into buffer 0
    #pragma unroll
    for (int j = 0; j < 4; ++j) gl_lds16(gK[j], lK[j]);

    for (int t = 0; t < 16; ++t) {
        const int cur = t & 1;
        const int k0 = t * 128;

        // stage V(t); prefetch K(t+1) into other buffer
        #pragma unroll
        for (int j = 0; j < 4; ++j) gl_lds16(gV[j] + k0, lV[j]);
        if (t < 15) {
            const int stoff = (cur ^ 1) * 8192;
            #pragma unroll
            for (int j = 0; j < 4; ++j)
                gl_lds16(gK[j] + (size_t)(t + 1) * (128 * 1024), lK[j] + stoff);
        }
        if (t == 0) {          // K(0) landed (V(0)+K(1) = 8 still in flight)
            WAITVM(8);
            PHASE_BARRIER();
        }
        const unsigned short* Kfr = KfrB + cur * 8192;

        #pragma unroll
        for (int cc = 0; cc < 2; ++cc) {          // two 64-key chunks
            // ---- QK^T, all 4 halves share each kf read ----
            f32x4 st[4][4] = {};
            #pragma unroll
            for (int ti = 0; ti < 4; ++ti)
                #pragma unroll
                for (int dblk = 0; dblk < 2; ++dblk) {
                    bf16x8 kf = *(const bf16x8*)(Kfr + ((cc * 4 + ti) * 2 + dblk) * 512);
                    #pragma unroll
                    for (int half = 0; half < 4; ++half)
                        st[half][ti] = __builtin_amdgcn_mfma_f32_16x16x32_bf16(
                            kf, qf[half][dblk], st[half][ti], 0, 0, 0);
                }

            // ---- p = exp2(s); pack (RHU) into per-half P regions ----
            #pragma unroll
            for (int half = 0; half < 4; ++half) {
                unsigned short* pw = PwB + half * 1024;
                #pragma unroll
                for (int ti = 0; ti < 4; ++ti) {
                    unsigned u0 = __float_as_uint(EXP2F(st[half][ti][0])) + 0x8000u;
                    unsigned u1 = __float_as_uint(EXP2F(st[half][ti][1])) + 0x8000u;
                    unsigned u2 = __float_as_uint(EXP2F(st[half][ti][2])) + 0x8000u;
                    unsigned u3 = __float_as_uint(EXP2F(st[half][ti][3])) + 0x8000u;
                    uint2 pk;
                    pk.x = __builtin_amdgcn_perm(u1, u0, 0x07060302);
                    pk.y = __builtin_amdgcn_perm(u3, u2, 0x07060302);
                    *(uint2*)(pw + ti * 256) = pk;
                }
            }

            // ---- after chunk0's compute has covered V latency: V ready ----
            if (cc == 0) {
                if (t < 15) { WAITVM(4); } else { WAITVM(0); }
                PHASE_BARRIER();      // Vs visible to all waves
            }

            // ---- PV + ones row-sum; vf read once per (nt,hbl), shared ----
            #pragma unroll
            for (int hbl = 0; hbl < 2; ++hbl) {
                bf16x8 pf[4];
                #pragma unroll
                for (int half = 0; half < 4; ++half) {
                    pf[half] = *(const bf16x8*)(PrB + half * 1024 + hbl * 512);
                    lacc[half] = __builtin_amdgcn_mfma_f32_16x16x32_bf16(
                        pf[half], ones, lacc[half], 0, 0, 0);
                }
                int hb = cc * 2 + hbl;
                #pragma unroll
                for (int nt = 0; nt < 4; ++nt) {
                    bf16x8 vf = *(const bf16x8*)(Vfr + (nt * 4 + hb) * 512);
                    #pragma unroll
                    for (int half = 0; half < 4; ++half)
                        oacc[half][nt] = __builtin_amdgcn_mfma_f32_16x16x32_bf16(
                            pf[half], vf, oacc[half][nt], 0, 0, 0);
                }
            }
        }

        if (t < 15) {
            WAITVM(0);        // K(t+1): issued a full tile of MFMA ago — free
            PHASE_BARRIER();  // K visible; Vs safe to overwrite next tile
        }
    }

    // ---- normalize + store ----
    #pragma unroll
    for (int half = 0; half < 4; ++half) {
        float il[4];
        #pragma unroll
        for (int r = 0; r < 4; ++r) il[r] = 1.0f / lacc[half][r];
        #pragma unroll
        for (int nt = 0; nt < 4; ++nt) {
            #pragma unroll
            for (int r = 0; r < 4; ++r) {
                size_t orow = (size_t)(b * LQ_ + qt * 256 + w * 64 + half * 16 + quad * 4 + r);
                Out[orow * 1024 + h * 64 + nt * 16 + l15] = oacc[half][nt][r] * il[r];
            }
        }
    }
}

// ---------------------------------------------------------------------------
extern "C" void kernel_launch(void* const* d_in, const int* in_sizes, int n_in,
                              void* d_out, int out_size, void* d_ws, size_t ws_size,
                              hipStream_t stream) {
    const float* zt = (const float*)d_in[0];
    const float* ic = (const float*)d_in[1];
    const float* Wq = (const float*)d_in[2];
    const float* bq = (const float*)d_in[3];
    const float* Wk = (const float*)d_in[4];
    const float* bk = (const float*)d_in[5];
    const float* Wv = (const float*)d_in[6];
    const float* bv = (const float*)d_in[7];
    float* out = (float*)d_out;

    const size_t M8 = (size_t)8192 * 1024;
    const size_t M1 = (size_t)1024 * 1024;
    unsigned short* Qb  = (unsigned short*)d_ws;
    unsigned short* Kb  = Qb  + M8;
    unsigned short* Vtb = Kb  + M8;          // V written transposed by qkv_gemm
    unsigned short* Xz  = Vtb + M8;
    unsigned short* Xi  = Xz  + M8;
    unsigned short* Wqb = Xi  + M8;
    unsigned short* Wkb = Wqb + M1;
    unsigned short* Wvb = Wkb + M1;

    const float qscale = 0.125f * 1.44269504088896f;  // 1/sqrt(64) * log2(e)

    dim3 gcv(4096, 5);
    cvt_all<<<gcv, 256, 0, stream>>>(zt, Xz, ic, Xi,
                                     Wq, Wqb, qscale, Wk, Wkb, Wv, Wvb,
                                     (int)M8, (int)M1);

    qkv_gemm<<<dim3(384), 512, 0, stream>>>(Xz, Xi, Wqb, Wkb, Wvb,
                                            bq, bk, bv, qscale, Qb, Kb, Vtb);

    dim3 gattn(8, 16, 4);                    // flattened+swizzled inside kernel
    attn_kernel<<<gattn, 256, 0, stream>>>(Qb, Kb, Vtb, out);
}

// Round 11
// 288.777 us; speedup vs baseline: 2.7567x; 1.0280x over previous
//
#include <hip/hip_runtime.h>
#include <hip/hip_bf16.h>
#include <cstdint>

#define B_  4
#define LQ_ 2048
#define LK_ 2048
#define D_  1024
#define H_  16
#define HD_ 64

typedef __attribute__((ext_vector_type(8))) short bf16x8;   // 8 bf16 in 4 VGPRs
typedef __attribute__((ext_vector_type(4))) float f32x4;    // MFMA C/D

#if defined(__has_builtin)
#if __has_builtin(__builtin_amdgcn_exp2f)
#define EXP2F(x) __builtin_amdgcn_exp2f(x)
#else
#define EXP2F(x) exp2f(x)
#endif
#else
#define EXP2F(x) exp2f(x)
#endif

__device__ __forceinline__ unsigned short f2b(float f) {   // RNE
    union { float f; unsigned u; } v; v.f = f;
    unsigned u = v.u;
    unsigned r = (u + 0x7fffu + ((u >> 16) & 1u)) >> 16;
    return (unsigned short)r;
}

// async global->LDS, 16B per lane. LDS dest: wave-uniform base + lane*16.
__device__ __forceinline__ void gl_lds16(const unsigned short* g, unsigned short* l) {
    __builtin_amdgcn_global_load_lds(
        (const __attribute__((address_space(1))) unsigned int*)(g),
        (__attribute__((address_space(3))) unsigned int*)(l),
        16, 0, 0);
}

#define PHASE_BARRIER() do { \
    __builtin_amdgcn_sched_barrier(0); \
    __builtin_amdgcn_s_barrier(); \
    __builtin_amdgcn_sched_barrier(0); } while (0)

#define WAITVM(N) do { \
    asm volatile("s_waitcnt vmcnt(" #N ")" ::: "memory"); \
    __builtin_amdgcn_sched_barrier(0); } while (0)

// ---------------------------------------------------------------------------
// Fused fp32->bf16 for all 5 tensors; blockIdx.y selects. Wq scaled by s0.
// (round-6 config: grid (4096,5), one-shot blocks.)
// ---------------------------------------------------------------------------
__global__ void cvt_all(const float* __restrict__ a0, unsigned short* __restrict__ d0,
                        const float* __restrict__ a1, unsigned short* __restrict__ d1,
                        const float* __restrict__ w0, unsigned short* __restrict__ e0, float s0,
                        const float* __restrict__ w1, unsigned short* __restrict__ e1,
                        const float* __restrict__ w2, unsigned short* __restrict__ e2,
                        int nact, int nw) {
    const float* in; unsigned short* out; float s = 1.0f; int n;
    switch (blockIdx.y) {
        case 0: in = a0; out = d0; n = nact; break;
        case 1: in = a1; out = d1; n = nact; break;
        case 2: in = w0; out = e0; n = nw; s = s0; break;
        case 3: in = w1; out = e1; n = nw; break;
        default: in = w2; out = e2; n = nw; break;
    }
    int i = (blockIdx.x * blockDim.x + threadIdx.x) * 8;
    int stride = gridDim.x * blockDim.x * 8;
    for (; i < n; i += stride) {
        float4 x = *(const float4*)(in + i);
        float4 y = *(const float4*)(in + i + 4);
        bf16x8 v;
        v[0] = (short)f2b(x.x * s); v[1] = (short)f2b(x.y * s);
        v[2] = (short)f2b(x.z * s); v[3] = (short)f2b(x.w * s);
        v[4] = (short)f2b(y.x * s); v[5] = (short)f2b(y.y * s);
        v[6] = (short)f2b(y.z * s); v[7] = (short)f2b(y.w * s);
        *(bf16x8*)(out + i) = v;
    }
}

// ---------------------------------------------------------------------------
// Fused QKV projection GEMM — round-6 exact (best measured): 256x256 tile,
// BK=64, 8 waves (2M x 4N), 4-phase counted-vmcnt (T3+T4+T5), 4-slot
// half-tile LDS ring (128KB), grid (32,12); natural dispatch already gives
// same-XCD X-panel locality (bid stride 32 = 0 mod 8; explicit remap was
// neutral, r9). V written directly transposed (r6).
// ---------------------------------------------------------------------------
__global__ __launch_bounds__(512, 2) void qkv_gemm(
    const unsigned short* __restrict__ Xq,
    const unsigned short* __restrict__ Xkv,
    const unsigned short* __restrict__ Wqb, const unsigned short* __restrict__ Wkb,
    const unsigned short* __restrict__ Wvb,
    const float* __restrict__ bq, const float* __restrict__ bk,
    const float* __restrict__ bv, float qscale,
    unsigned short* __restrict__ Qb, unsigned short* __restrict__ Kb,
    unsigned short* __restrict__ Vtb)
{
    __shared__ unsigned short AS[4][8192];   // slot (2t+kh)&3 : 16 frags x 512
    __shared__ unsigned short BS[4][8192];

    const int proj = blockIdx.y >> 2;
    const int nt0  = blockIdx.y & 3;
    const unsigned short* X = (proj == 0) ? Xq : Xkv;
    const unsigned short* W = (proj == 0) ? Wqb : (proj == 1 ? Wkb : Wvb);
    const float* bias       = (proj == 0) ? bq  : (proj == 1 ? bk  : bv);
    const float bscale      = (proj == 0) ? qscale : 1.0f;

    const int tid  = threadIdx.x;
    const int lane = tid & 63;
    const int w    = tid >> 6;                 // 0..7
    const int wm   = w & 1, wn = w >> 1;       // 2M x 4N wave grid
    const int m0   = blockIdx.x * 256;
    const int n0   = nt0 * 256;
    const int l15  = lane & 15, quad = lane >> 4;

    f32x4 acc[8][4] = {};

    // staging sources: wave w stages frags w*2, w*2+1 of each 16-frag half
    const unsigned short* gA0 = X + (size_t)(m0 + (w * 2) * 16 + l15) * 1024 + quad * 8;
    const unsigned short* gA1 = gA0 + 16 * 1024;
    const unsigned short* gB0 = W + (size_t)(n0 + (w * 2) * 16 + l15) * 1024 + quad * 8;
    const unsigned short* gB1 = gB0 + 16 * 1024;

#define STAGE_A(slot, koff) do { \
    gl_lds16(gA0 + (koff), &AS[slot][(w * 2) * 512 + lane * 8]); \
    gl_lds16(gA1 + (koff), &AS[slot][(w * 2 + 1) * 512 + lane * 8]); } while (0)
#define STAGE_B(slot, koff) do { \
    gl_lds16(gB0 + (koff), &BS[slot][(w * 2) * 512 + lane * 8]); \
    gl_lds16(gB1 + (koff), &BS[slot][(w * 2 + 1) * 512 + lane * 8]); } while (0)

    const int aoff = (wm * 8) * 512 + lane * 8;   // my 8 m-frags
    const int boff = (wn * 4) * 512 + lane * 8;   // my 4 n-frags

    // prologue: tiles 0 (both halves) + tile 1 kh0, in ring-issue order
    STAGE_A(0, 0);   STAGE_B(0, 0);
    STAGE_A(1, 32);  STAGE_B(1, 32);
    STAGE_A(2, 64);  STAGE_B(2, 64);
    WAITVM(8);
    __builtin_amdgcn_s_barrier();
    __builtin_amdgcn_sched_barrier(0);

    #pragma unroll 2
    for (int t = 0; t < 16; ++t) {
        const int s0 = (2 * t) & 3;
        const int s1 = (2 * t + 1) & 3;
        const int s3 = (2 * t + 3) & 3;

        bf16x8 af[8], bf0, bf1;

        // ---- P1: kh0, n-frags 0,1 ----
        #pragma unroll
        for (int i = 0; i < 8; ++i)
            af[i] = *(const bf16x8*)(&AS[s0][aoff + i * 512]);
        bf0 = *(const bf16x8*)(&BS[s0][boff]);
        bf1 = *(const bf16x8*)(&BS[s0][boff + 512]);
        PHASE_BARRIER();
        __builtin_amdgcn_s_setprio(1);
        #pragma unroll
        for (int i = 0; i < 8; ++i) {
            acc[i][0] = __builtin_amdgcn_mfma_f32_16x16x32_bf16(af[i], bf0, acc[i][0], 0, 0, 0);
            acc[i][1] = __builtin_amdgcn_mfma_f32_16x16x32_bf16(af[i], bf1, acc[i][1], 0, 0, 0);
        }
        __builtin_amdgcn_s_setprio(0);
        if (t < 15) STAGE_A(s3, (t + 1) * 64 + 32);

        // ---- P2: kh0, n-frags 2,3 (af reused) ----
        bf0 = *(const bf16x8*)(&BS[s0][boff + 1024]);
        bf1 = *(const bf16x8*)(&BS[s0][boff + 1536]);
        if (t < 14) { WAITVM(6); } else { WAITVM(0); }
        PHASE_BARRIER();
        __builtin_amdgcn_s_setprio(1);
        #pragma unroll
        for (int i = 0; i < 8; ++i) {
            acc[i][2] = __builtin_amdgcn_mfma_f32_16x16x32_bf16(af[i], bf0, acc[i][2], 0, 0, 0);
            acc[i][3] = __builtin_amdgcn_mfma_f32_16x16x32_bf16(af[i], bf1, acc[i][3], 0, 0, 0);
        }
        __builtin_amdgcn_s_setprio(0);
        if (t < 15) STAGE_B(s3, (t + 1) * 64 + 32);

        // ---- P3: kh1, n-frags 0,1 ----
        #pragma unroll
        for (int i = 0; i < 8; ++i)
            af[i] = *(const bf16x8*)(&AS[s1][aoff + i * 512]);
        bf0 = *(const bf16x8*)(&BS[s1][boff]);
        bf1 = *(const bf16x8*)(&BS[s1][boff + 512]);
        PHASE_BARRIER();
        __builtin_amdgcn_s_setprio(1);
        #pragma unroll
        for (int i = 0; i < 8; ++i) {
            acc[i][0] = __builtin_amdgcn_mfma_f32_16x16x32_bf16(af[i], bf0, acc[i][0], 0, 0, 0);
            acc[i][1] = __builtin_amdgcn_mfma_f32_16x16x32_bf16(af[i], bf1, acc[i][1], 0, 0, 0);
        }
        __builtin_amdgcn_s_setprio(0);
        if (t < 14) STAGE_A(s0, (t + 2) * 64);

        // ---- P4: kh1, n-frags 2,3 ----
        bf0 = *(const bf16x8*)(&BS[s1][boff + 1024]);
        bf1 = *(const bf16x8*)(&BS[s1][boff + 1536]);
        if (t < 14) { WAITVM(6); } else if (t == 14) { WAITVM(4); }
        PHASE_BARRIER();
        __builtin_amdgcn_s_setprio(1);
        #pragma unroll
        for (int i = 0; i < 8; ++i) {
            acc[i][2] = __builtin_amdgcn_mfma_f32_16x16x32_bf16(af[i], bf0, acc[i][2], 0, 0, 0);
            acc[i][3] = __builtin_amdgcn_mfma_f32_16x16x32_bf16(af[i], bf1, acc[i][3], 0, 0, 0);
        }
        __builtin_amdgcn_s_setprio(0);
        if (t < 14) STAGE_B(s0, (t + 2) * 64);
    }

#undef STAGE_A
#undef STAGE_B

    float bvv[4];
    #pragma unroll
    for (int j = 0; j < 4; ++j)
        bvv[j] = bias[n0 + wn * 64 + j * 16 + l15] * bscale;

    if (proj == 2) {
        // ---- transposed epilogue: write Vt[(b*1024+col)*2048 + tok] ----
        #pragma unroll
        for (int i = 0; i < 8; ++i) {
            int row = m0 + wm * 128 + i * 16 + quad * 4;   // token base (r=0..3)
            int bb  = row >> 11;
            int tt  = row & 2047;
            #pragma unroll
            for (int j = 0; j < 4; ++j) {
                int col = n0 + wn * 64 + j * 16 + l15;
                unsigned s0v = f2b(acc[i][j][0] + bvv[j]);
                unsigned s1v = f2b(acc[i][j][1] + bvv[j]);
                unsigned s2v = f2b(acc[i][j][2] + bvv[j]);
                unsigned s3v = f2b(acc[i][j][3] + bvv[j]);
                uint2 pk;
                pk.x = s0v | (s1v << 16);
                pk.y = s2v | (s3v << 16);
                *(uint2*)(Vtb + ((size_t)(bb * 1024 + col)) * 2048 + tt) = pk;
            }
        }
    } else {
        unsigned short* Y = (proj == 0) ? Qb : Kb;
        #pragma unroll
        for (int i = 0; i < 8; ++i) {
            #pragma unroll
            for (int r = 0; r < 4; ++r) {
                int row = m0 + wm * 128 + i * 16 + quad * 4 + r;
                unsigned short* yp = Y + (size_t)row * 1024 + n0 + wn * 64;
                #pragma unroll
                for (int j = 0; j < 4; ++j)
                    yp[j * 16 + l15] = f2b(acc[i][j][r] + bvv[j]);
            }
        }
    }
}

// ---------------------------------------------------------------------------
// Flash attention v8 — round-6 exact (measured 97.2us, correct): shared LDS
// staging of K and V + XCD swizzle + K double-buffer, counted waits,
// perm-based RHU P-pack (r10 lesson: v_cvt_pk_bf16_f32 inline asm has
// different semantics on gfx950 — broke correctness; do not hand-write).
// LDS: K dbuf 32K + Vs 16K + Ps 32K = 80KB -> 2 blocks/CU.
// ---------------------------------------------------------------------------
__global__ __launch_bounds__(256, 2) void attn_kernel(
    const unsigned short* __restrict__ Q,
    const unsigned short* __restrict__ Kp,
    const unsigned short* __restrict__ Vt,
    float* __restrict__ Out)
{
    __shared__ unsigned short Ks[2][16 * 512]; // frag f=kt*2+dblk: K[kt*16+l15][dblk*32+quad*8+j]
    __shared__ unsigned short Vs[16 * 512];    // frag f=nt*4+hb:  V^T[nt*16+l15][hb*32+quad*8+j]
    __shared__ unsigned short Ps[4][4096];     // per-wave, per-half 1024: P[16q][64k] frag-ordered

    const int tid  = threadIdx.x;
    const int lane = tid & 63;
    const int w    = tid >> 6;
    const int l15  = lane & 15, quad = lane >> 4;

    // XCD swizzle: all 8 q-tiles of a (b,h) group share bid%8 -> same XCD,
    // K/V stay L2-resident (proven r2: FETCH 141MB -> 25MB).
    const int bid = blockIdx.x + (blockIdx.y << 3) + (blockIdx.z << 7);
    const int glo = bid & 7;
    const int jx  = bid >> 3;          // 0..63
    const int qt  = jx & 7;
    const int g   = glo + ((jx >> 3) << 3);   // 0..63: (b,h) group
    const int h   = g & 15;
    const int b   = g >> 4;

    bf16x8 qf[4][2];
    #pragma unroll
    for (int half = 0; half < 4; ++half) {
        const unsigned short* qptr =
            Q + (size_t)(b * LQ_ + qt * 256 + w * 64 + half * 16 + l15) * 1024 + h * 64;
        qf[half][0] = *(const bf16x8*)(qptr + quad * 8);
        qf[half][1] = *(const bf16x8*)(qptr + 32 + quad * 8);
    }

    bf16x8 ones;
    #pragma unroll
    for (int j = 0; j < 8; ++j) ones[j] = (short)0x3F80;   // bf16 1.0

    f32x4 oacc[4][4] = {};
    f32x4 lacc[4]    = {};

    const unsigned short* Kbase = Kp + (size_t)b * LK_ * 1024 + h * 64;
    const unsigned short* Vbase = Vt + (size_t)(b * 16 + h) * 64 * 2048;

    const unsigned short* gK[4];
    unsigned short* lK[4];                    // buffer-0 LDS dests
    const unsigned short* gV[4];
    unsigned short* lV[4];
    #pragma unroll
    for (int j = 0; j < 4; ++j) {
        int kt = w + (j >> 1) * 4, dblk = j & 1;
        gK[j] = Kbase + (size_t)(kt * 16 + l15) * 1024 + dblk * 32 + quad * 8;
        lK[j] = &Ks[0][(kt * 2 + dblk) * 512 + lane * 8];
        gV[j] = Vbase + (size_t)(w * 16 + l15) * 2048 + j * 32 + quad * 8;
        lV[j] = &Vs[(w * 4 + j) * 512 + lane * 8];
    }

    // P region: element (q,k) at half*1024 + (k>>3)*128 + q*8 + (k&7)
    const int pws = (quad >> 1) * 128 + l15 * 8 + (quad & 1) * 4;
    unsigned short* PwB = &Ps[w][pws];            // + half*1024 + ti*256
    const unsigned short* PrB = &Ps[w][lane * 8]; // + half*1024 + hbl*512
    const unsigned short* KfrB = &Ks[0][lane * 8];
    const unsigned short* Vfr = &Vs[lane * 8];

    // prologue: stage K(0) into buffer 0
    #pragma unroll
    for (int j = 0; j < 4; ++j) gl_lds16(gK[j], lK[j]);

    for (int t = 0; t < 16; ++t) {
        const int cur = t & 1;
        const int k0 = t * 128;

        // stage V(t); prefetch K(t+1) into other buffer
        #pragma unroll
        for (int j = 0; j < 4; ++j) gl_lds16(gV[j] + k0, lV[j]);
        if (t < 15) {
            const int stoff = (cur ^ 1) * 8192;
            #pragma unroll
            for (int j = 0; j < 4; ++j)
                gl_lds16(gK[j] + (size_t)(t + 1) * (128 * 1024), lK[j] + stoff);
        }
        if (t == 0) {          // K(0) landed (V(0)+K(1) = 8 still in flight)
            WAITVM(8);
            PHASE_BARRIER();
        }
        const unsigned short* Kfr = KfrB + cur * 8192;

        #pragma unroll
        for (int cc = 0; cc < 2; ++cc) {          // two 64-key chunks
            // ---- QK^T, all 4 halves share each kf read ----
            f32x4 st[4][4] = {};
            #pragma unroll
            for (int ti = 0; ti < 4; ++ti)
                #pragma unroll
                for (int dblk = 0; dblk < 2; ++dblk) {
                    bf16x8 kf = *(const bf16x8*)(Kfr + ((cc * 4 + ti) * 2 + dblk) * 512);
                    #pragma unroll
                    for (int half = 0; half < 4; ++half)
                        st[half][ti] = __builtin_amdgcn_mfma_f32_16x16x32_bf16(
                            kf, qf[half][dblk], st[half][ti], 0, 0, 0);
                }

            // ---- p = exp2(s); pack (RHU) into per-half P regions ----
            #pragma unroll
            for (int half = 0; half < 4; ++half) {
                unsigned short* pw = PwB + half * 1024;
                #pragma unroll
                for (int ti = 0; ti < 4; ++ti) {
                    unsigned u0 = __float_as_uint(EXP2F(st[half][ti][0])) + 0x8000u;
                    unsigned u1 = __float_as_uint(EXP2F(st[half][ti][1])) + 0x8000u;
                    unsigned u2 = __float_as_uint(EXP2F(st[half][ti][2])) + 0x8000u;
                    unsigned u3 = __float_as_uint(EXP2F(st[half][ti][3])) + 0x8000u;
                    uint2 pk;
                    pk.x = __builtin_amdgcn_perm(u1, u0, 0x07060302);
                    pk.y = __builtin_amdgcn_perm(u3, u2, 0x07060302);
                    *(uint2*)(pw + ti * 256) = pk;
                }
            }

            // ---- after chunk0's compute has covered V latency: V ready ----
            if (cc == 0) {
                if (t < 15) { WAITVM(4); } else { WAITVM(0); }
                PHASE_BARRIER();      // Vs visible to all waves
            }

            // ---- PV + ones row-sum; vf read once per (nt,hbl), shared ----
            #pragma unroll
            for (int hbl = 0; hbl < 2; ++hbl) {
                bf16x8 pf[4];
                #pragma unroll
                for (int half = 0; half < 4; ++half) {
                    pf[half] = *(const bf16x8*)(PrB + half * 1024 + hbl * 512);
                    lacc[half] = __builtin_amdgcn_mfma_f32_16x16x32_bf16(
                        pf[half], ones, lacc[half], 0, 0, 0);
                }
                int hb = cc * 2 + hbl;
                #pragma unroll
                for (int nt = 0; nt < 4; ++nt) {
                    bf16x8 vf = *(const bf16x8*)(Vfr + (nt * 4 + hb) * 512);
                    #pragma unroll
                    for (int half = 0; half < 4; ++half)
                        oacc[half][nt] = __builtin_amdgcn_mfma_f32_16x16x32_bf16(
                            pf[half], vf, oacc[half][nt], 0, 0, 0);
                }
            }
        }

        if (t < 15) {
            WAITVM(0);        // K(t+1): issued a full tile of MFMA ago — free
            PHASE_BARRIER();  // K visible; Vs safe to overwrite next tile
        }
    }

    // ---- normalize + store ----
    #pragma unroll
    for (int half = 0; half < 4; ++half) {
        float il[4];
        #pragma unroll
        for (int r = 0; r < 4; ++r) il[r] = 1.0f / lacc[half][r];
        #pragma unroll
        for (int nt = 0; nt < 4; ++nt) {
            #pragma unroll
            for (int r = 0; r < 4; ++r) {
                size_t orow = (size_t)(b * LQ_ + qt * 256 + w * 64 + half * 16 + quad * 4 + r);
                Out[orow * 1024 + h * 64 + nt * 16 + l15] = oacc[half][nt][r] * il[r];
            }
        }
    }
}

// ---------------------------------------------------------------------------
extern "C" void kernel_launch(void* const* d_in, const int* in_sizes, int n_in,
                              void* d_out, int out_size, void* d_ws, size_t ws_size,
                              hipStream_t stream) {
    const float* zt = (const float*)d_in[0];
    const float* ic = (const float*)d_in[1];
    const float* Wq = (const float*)d_in[2];
    const float* bq = (const float*)d_in[3];
    const float* Wk = (const float*)d_in[4];
    const float* bk = (const float*)d_in[5];
    const float* Wv = (const float*)d_in[6];
    const float* bv = (const float*)d_in[7];
    float* out = (float*)d_out;

    const size_t M8 = (size_t)8192 * 1024;
    const size_t M1 = (size_t)1024 * 1024;
    unsigned short* Qb  = (unsigned short*)d_ws;
    unsigned short* Kb  = Qb  + M8;
    unsigned short* Vtb = Kb  + M8;          // V written transposed by qkv_gemm
    unsigned short* Xz  = Vtb + M8;
    unsigned short* Xi  = Xz  + M8;
    unsigned short* Wqb = Xi  + M8;
    unsigned short* Wkb = Wqb + M1;
    unsigned short* Wvb = Wkb + M1;

    const float qscale = 0.125f * 1.44269504088896f;  // 1/sqrt(64) * log2(e)

    dim3 gcv(4096, 5);
    cvt_all<<<gcv, 256, 0, stream>>>(zt, Xz, ic, Xi,
                                     Wq, Wqb, qscale, Wk, Wkb, Wv, Wvb,
                                     (int)M8, (int)M1);

    dim3 gproj(32, 12);                      // m-tile (8192/256), proj*4 + n-tile
    qkv_gemm<<<gproj, 512, 0, stream>>>(Xz, Xi, Wqb, Wkb, Wvb,
                                        bq, bk, bv, qscale, Qb, Kb, Vtb);

    dim3 gattn(8, 16, 4);                    // flattened+swizzled inside kernel
    attn_kernel<<<gattn, 256, 0, stream>>>(Qb, Kb, Vtb, out);
}

// Round 14
// 284.588 us; speedup vs baseline: 2.7973x; 1.0147x over previous
//
#include <hip/hip_runtime.h>
#include <hip/hip_bf16.h>
#include <cstdint>

#define B_  4
#define LQ_ 2048
#define LK_ 2048
#define D_  1024
#define H_  16
#define HD_ 64

typedef __attribute__((ext_vector_type(8))) short bf16x8;   // 8 bf16 in 4 VGPRs
typedef __attribute__((ext_vector_type(4))) float f32x4;    // MFMA C/D

#if defined(__has_builtin)
#if __has_builtin(__builtin_amdgcn_exp2f)
#define EXP2F(x) __builtin_amdgcn_exp2f(x)
#else
#define EXP2F(x) exp2f(x)
#endif
#else
#define EXP2F(x) exp2f(x)
#endif

__device__ __forceinline__ unsigned short f2b(float f) {   // RNE
    union { float f; unsigned u; } v; v.f = f;
    unsigned u = v.u;
    unsigned r = (u + 0x7fffu + ((u >> 16) & 1u)) >> 16;
    return (unsigned short)r;
}

// async global->LDS, 16B per lane. LDS dest: wave-uniform base + lane*16.
__device__ __forceinline__ void gl_lds16(const unsigned short* g, unsigned short* l) {
    __builtin_amdgcn_global_load_lds(
        (const __attribute__((address_space(1))) unsigned int*)(g),
        (__attribute__((address_space(3))) unsigned int*)(l),
        16, 0, 0);
}

#define PHASE_BARRIER() do { \
    __builtin_amdgcn_sched_barrier(0); \
    __builtin_amdgcn_s_barrier(); \
    __builtin_amdgcn_sched_barrier(0); } while (0)

#define WAITVM(N) do { \
    asm volatile("s_waitcnt vmcnt(" #N ")" ::: "memory"); \
    __builtin_amdgcn_sched_barrier(0); } while (0)

// ---------------------------------------------------------------------------
// Fused fp32->bf16 for all 5 tensors; blockIdx.y selects. Wq scaled by s0.
// ---------------------------------------------------------------------------
__global__ void cvt_all(const float* __restrict__ a0, unsigned short* __restrict__ d0,
                        const float* __restrict__ a1, unsigned short* __restrict__ d1,
                        const float* __restrict__ w0, unsigned short* __restrict__ e0, float s0,
                        const float* __restrict__ w1, unsigned short* __restrict__ e1,
                        const float* __restrict__ w2, unsigned short* __restrict__ e2,
                        int nact, int nw) {
    const float* in; unsigned short* out; float s = 1.0f; int n;
    switch (blockIdx.y) {
        case 0: in = a0; out = d0; n = nact; break;
        case 1: in = a1; out = d1; n = nact; break;
        case 2: in = w0; out = e0; n = nw; s = s0; break;
        case 3: in = w1; out = e1; n = nw; break;
        default: in = w2; out = e2; n = nw; break;
    }
    int i = (blockIdx.x * blockDim.x + threadIdx.x) * 8;
    int stride = gridDim.x * blockDim.x * 8;
    for (; i < n; i += stride) {
        float4 x = *(const float4*)(in + i);
        float4 y = *(const float4*)(in + i + 4);
        bf16x8 v;
        v[0] = (short)f2b(x.x * s); v[1] = (short)f2b(x.y * s);
        v[2] = (short)f2b(x.z * s); v[3] = (short)f2b(x.w * s);
        v[4] = (short)f2b(y.x * s); v[5] = (short)f2b(y.y * s);
        v[6] = (short)f2b(y.z * s); v[7] = (short)f2b(y.w * s);
        *(bf16x8*)(out + i) = v;
    }
}

// ---------------------------------------------------------------------------
// Fused QKV projection GEMM v4 -- 256x128 tile (MxN), BK processed as 32
// kh-halves (32 elems each), 8 waves (2M x 4N: per wave 8 m-frags x 2
// n-frags, acc = 64 regs). Keeps 16 MFMA per phase (r4 lesson) and stays
// 1 block/CU with no reg split (r8 lesson); grid = 32 m-tiles x 24
// (proj x 8 n-tiles) = 768 = 256 CUs x 3 exactly -- removes the 1.5-round
// imbalance of the 256x256 grid (384 blocks: 25% CU-idle in round 2).
// Counted-vmcnt ladder, 3 gl_lds per wave per slot (2 A + 1 B), 4-slot
// ring (A 4x16KB + B 4x8KB = 96KB LDS): phase g waits vmcnt(6) [drains
// slot g's 3 loads; slots g+1,g+2 in flight] -> barrier -> ds_read 10
// frags -> 16 MFMA (setprio) -> stage slot g+3. Tail: g=29,30 no stage;
// g=30 waits 3; g=31 waits 0. V (proj==2) written directly transposed.
// ---------------------------------------------------------------------------
__global__ __launch_bounds__(512, 2) void qkv_gemm(
    const unsigned short* __restrict__ Xq,
    const unsigned short* __restrict__ Xkv,
    const unsigned short* __restrict__ Wqb, const unsigned short* __restrict__ Wkb,
    const unsigned short* __restrict__ Wvb,
    const float* __restrict__ bq, const float* __restrict__ bk,
    const float* __restrict__ bv, float qscale,
    unsigned short* __restrict__ Qb, unsigned short* __restrict__ Kb,
    unsigned short* __restrict__ Vtb)
{
    __shared__ unsigned short AS[4][16 * 512];   // slot g&3: 16 A-frags
    __shared__ unsigned short BS[4][8 * 512];    // slot g&3:  8 B-frags

    const int proj = blockIdx.y >> 3;
    const int nt0  = blockIdx.y & 7;
    const unsigned short* X = (proj == 0) ? Xq : Xkv;
    const unsigned short* W = (proj == 0) ? Wqb : (proj == 1 ? Wkb : Wvb);
    const float* bias       = (proj == 0) ? bq  : (proj == 1 ? bk  : bv);
    const float bscale      = (proj == 0) ? qscale : 1.0f;

    const int tid  = threadIdx.x;
    const int lane = tid & 63;
    const int w    = tid >> 6;                 // 0..7
    const int wm   = w & 1, wn = w >> 1;       // 2M x 4N wave grid
    const int m0   = blockIdx.x * 256;
    const int n0   = nt0 * 128;
    const int l15  = lane & 15, quad = lane >> 4;

    f32x4 acc[8][2] = {};

    // staging: wave w owns A-frags w*2, w*2+1 and B-frag w of each slot
    const unsigned short* gA0 = X + (size_t)(m0 + (w * 2) * 16 + l15) * 1024 + quad * 8;
    const unsigned short* gA1 = gA0 + 16 * 1024;
    const unsigned short* gB0 = W + (size_t)(n0 + w * 16 + l15) * 1024 + quad * 8;

#define STAGE(slot, koff) do { \
    gl_lds16(gA0 + (koff), &AS[slot][(w * 2) * 512 + lane * 8]); \
    gl_lds16(gA1 + (koff), &AS[slot][(w * 2 + 1) * 512 + lane * 8]); \
    gl_lds16(gB0 + (koff), &BS[slot][w * 512 + lane * 8]); } while (0)

    const int aoff = (wm * 8) * 512 + lane * 8;   // my 8 m-frags
    const int boff = (wn * 2) * 512 + lane * 8;   // my 2 n-frags

    // prologue: slots 0,1,2 (kh-halves 0,1,2) -> 9 loads in flight
    STAGE(0, 0);
    STAGE(1, 32);
    STAGE(2, 64);

#define QPHASE(slot, WN, do_stage, sslot, skoff) do { \
    WAITVM(WN); \
    PHASE_BARRIER(); \
    bf16x8 af[8], b0, b1; \
    _Pragma("unroll") \
    for (int i = 0; i < 8; ++i) \
        af[i] = *(const bf16x8*)(&AS[slot][aoff + i * 512]); \
    b0 = *(const bf16x8*)(&BS[slot][boff]); \
    b1 = *(const bf16x8*)(&BS[slot][boff + 512]); \
    __builtin_amdgcn_s_setprio(1); \
    _Pragma("unroll") \
    for (int i = 0; i < 8; ++i) { \
        acc[i][0] = __builtin_amdgcn_mfma_f32_16x16x32_bf16(af[i], b0, acc[i][0], 0, 0, 0); \
        acc[i][1] = __builtin_amdgcn_mfma_f32_16x16x32_bf16(af[i], b1, acc[i][1], 0, 0, 0); \
    } \
    __builtin_amdgcn_s_setprio(0); \
    if (do_stage) STAGE(sslot, skoff); } while (0)

    #pragma unroll 2
    for (int t = 0; t < 16; ++t) {
        const int s0 = (2 * t) & 3;          // kh0 slot  (g = 2t)
        const int s1 = (2 * t + 1) & 3;      // kh1 slot  (g = 2t+1)
        const int sa = (2 * t + 3) & 3;      // staged by kh0 phase (g+3)
        const int sb = (2 * t + 4) & 3;      // staged by kh1 phase (g+3)

        if (t < 15) {
            QPHASE(s0, 6, 1, sa, (2 * t + 3) * 32);           // g = 0..28 even
        } else {
            QPHASE(s0, 3, 0, sa, 0);                          // g = 30: no stage
        }
        if (t < 15) {
            QPHASE(s1, 6, (t <= 13), sb, (2 * t + 4) * 32);   // g = 1..29 odd
        } else {
            QPHASE(s1, 0, 0, sb, 0);                          // g = 31: drain
        }
    }

#undef QPHASE
#undef STAGE

    float bvv[2];
    #pragma unroll
    for (int j = 0; j < 2; ++j)
        bvv[j] = bias[n0 + wn * 32 + j * 16 + l15] * bscale;

    if (proj == 2) {
        // ---- transposed epilogue: write Vt[(b*1024+col)*2048 + tok] ----
        #pragma unroll
        for (int i = 0; i < 8; ++i) {
            int row = m0 + wm * 128 + i * 16 + quad * 4;   // token base (r=0..3)
            int bb  = row >> 11;
            int tt  = row & 2047;
            #pragma unroll
            for (int j = 0; j < 2; ++j) {
                int col = n0 + wn * 32 + j * 16 + l15;
                unsigned s0v = f2b(acc[i][j][0] + bvv[j]);
                unsigned s1v = f2b(acc[i][j][1] + bvv[j]);
                unsigned s2v = f2b(acc[i][j][2] + bvv[j]);
                unsigned s3v = f2b(acc[i][j][3] + bvv[j]);
                uint2 pk;
                pk.x = s0v | (s1v << 16);
                pk.y = s2v | (s3v << 16);
                *(uint2*)(Vtb + ((size_t)(bb * 1024 + col)) * 2048 + tt) = pk;
            }
        }
    } else {
        unsigned short* Y = (proj == 0) ? Qb : Kb;
        #pragma unroll
        for (int i = 0; i < 8; ++i) {
            #pragma unroll
            for (int r = 0; r < 4; ++r) {
                int row = m0 + wm * 128 + i * 16 + quad * 4 + r;
                unsigned short* yp = Y + (size_t)row * 1024 + n0 + wn * 32;
                #pragma unroll
                for (int j = 0; j < 2; ++j)
                    yp[j * 16 + l15] = f2b(acc[i][j][r] + bvv[j]);
            }
        }
    }
}

// ---------------------------------------------------------------------------
// Flash attention v8 -- round-6/11 exact (measured 97-98us, correct):
// shared LDS staging of K and V + XCD swizzle + K double-buffer, counted
// waits, perm-based RHU P-pack. LDS: 80KB -> 2 blocks/CU.
// ---------------------------------------------------------------------------
__global__ __launch_bounds__(256, 2) void attn_kernel(
    const unsigned short* __restrict__ Q,
    const unsigned short* __restrict__ Kp,
    const unsigned short* __restrict__ Vt,
    float* __restrict__ Out)
{
    __shared__ unsigned short Ks[2][16 * 512]; // frag f=kt*2+dblk: K[kt*16+l15][dblk*32+quad*8+j]
    __shared__ unsigned short Vs[16 * 512];    // frag f=nt*4+hb:  V^T[nt*16+l15][hb*32+quad*8+j]
    __shared__ unsigned short Ps[4][4096];     // per-wave, per-half 1024: P[16q][64k] frag-ordered

    const int tid  = threadIdx.x;
    const int lane = tid & 63;
    const int w    = tid >> 6;
    const int l15  = lane & 15, quad = lane >> 4;

    // XCD swizzle: all 8 q-tiles of a (b,h) group share bid%8 -> same XCD,
    // K/V stay L2-resident (proven r2: FETCH 141MB -> 25MB).
    const int bid = blockIdx.x + (blockIdx.y << 3) + (blockIdx.z << 7);
    const int glo = bid & 7;
    const int jx  = bid >> 3;          // 0..63
    const int qt  = jx & 7;
    const int g   = glo + ((jx >> 3) << 3);   // 0..63: (b,h) group
    const int h   = g & 15;
    const int b   = g >> 4;

    bf16x8 qf[4][2];
    #pragma unroll
    for (int half = 0; half < 4; ++half) {
        const unsigned short* qptr =
            Q + (size_t)(b * LQ_ + qt * 256 + w * 64 + half * 16 + l15) * 1024 + h * 64;
        qf[half][0] = *(const bf16x8*)(qptr + quad * 8);
        qf[half][1] = *(const bf16x8*)(qptr + 32 + quad * 8);
    }

    bf16x8 ones;
    #pragma unroll
    for (int j = 0; j < 8; ++j) ones[j] = (short)0x3F80;   // bf16 1.0

    f32x4 oacc[4][4] = {};
    f32x4 lacc[4]    = {};

    const unsigned short* Kbase = Kp + (size_t)b * LK_ * 1024 + h * 64;
    const unsigned short* Vbase = Vt + (size_t)(b * 16 + h) * 64 * 2048;

    const unsigned short* gK[4];
    unsigned short* lK[4];                    // buffer-0 LDS dests
    const unsigned short* gV[4];
    unsigned short* lV[4];
    #pragma unroll
    for (int j = 0; j < 4; ++j) {
        int kt = w + (j >> 1) * 4, dblk = j & 1;
        gK[j] = Kbase + (size_t)(kt * 16 + l15) * 1024 + dblk * 32 + quad * 8;
        lK[j] = &Ks[0][(kt * 2 + dblk) * 512 + lane * 8];
        gV[j] = Vbase + (size_t)(w * 16 + l15) * 2048 + j * 32 + quad * 8;
        lV[j] = &Vs[(w * 4 + j) * 512 + lane * 8];
    }

    // P region: element (q,k) at half*1024 + (k>>3)*128 + q*8 + (k&7)
    const int pws = (quad >> 1) * 128 + l15 * 8 + (quad & 1) * 4;
    unsigned short* PwB = &Ps[w][pws];            // + half*1024 + ti*256
    const unsigned short* PrB = &Ps[w][lane * 8]; // + half*1024 + hbl*512
    const unsigned short* KfrB = &Ks[0][lane * 8];
    const unsigned short* Vfr = &Vs[lane * 8];

    // prologue: stage K(0) into buffer 0
    #pragma unroll
    for (int j = 0; j < 4; ++j) gl_lds16(gK[j], lK[j]);

    for (int t = 0; t < 16; ++t) {
        const int cur = t & 1;
        const int k0 = t * 128;

        // stage V(t); prefetch K(t+1) into other buffer
        #pragma unroll
        for (int j = 0; j < 4; ++j) gl_lds16(gV[j] + k0, lV[j]);
        if (t < 15) {
            const int stoff = (cur ^ 1) * 8192;
            #pragma unroll
            for (int j = 0; j < 4; ++j)
                gl_lds16(gK[j] + (size_t)(t + 1) * (128 * 1024), lK[j] + stoff);
        }
        if (t == 0) {          // K(0) landed (V(0)+K(1) = 8 still in flight)
            WAITVM(8);
            PHASE_BARRIER();
        }
        const unsigned short* Kfr = KfrB + cur * 8192;

        #pragma unroll
        for (int cc = 0; cc < 2; ++cc) {          // two 64-key chunks
            // ---- QK^T, all 4 halves share each kf read ----
            f32x4 st[4][4] = {};
            #pragma unroll
            for (int ti = 0; ti < 4; ++ti)
                #pragma unroll
                for (int dblk = 0; dblk < 2; ++dblk) {
                    bf16x8 kf = *(const bf16x8*)(Kfr + ((cc * 4 + ti) * 2 + dblk) * 512);
                    #pragma unroll
                    for (int half = 0; half < 4; ++half)
                        st[half][ti] = __builtin_amdgcn_mfma_f32_16x16x32_bf16(
                            kf, qf[half][dblk], st[half][ti], 0, 0, 0);
                }

            // ---- p = exp2(s); pack (RHU) into per-half P regions ----
            #pragma unroll
            for (int half = 0; half < 4; ++half) {
                unsigned short* pw = PwB + half * 1024;
                #pragma unroll
                for (int ti = 0; ti < 4; ++ti) {
                    unsigned u0 = __float_as_uint(EXP2F(st[half][ti][0])) + 0x8000u;
                    unsigned u1 = __float_as_uint(EXP2F(st[half][ti][1])) + 0x8000u;
                    unsigned u2 = __float_as_uint(EXP2F(st[half][ti][2])) + 0x8000u;
                    unsigned u3 = __float_as_uint(EXP2F(st[half][ti][3])) + 0x8000u;
                    uint2 pk;
                    pk.x = __builtin_amdgcn_perm(u1, u0, 0x07060302);
                    pk.y = __builtin_amdgcn_perm(u3, u2, 0x07060302);
                    *(uint2*)(pw + ti * 256) = pk;
                }
            }

            // ---- after chunk0's compute has covered V latency: V ready ----
            if (cc == 0) {
                if (t < 15) { WAITVM(4); } else { WAITVM(0); }
                PHASE_BARRIER();      // Vs visible to all waves
            }

            // ---- PV + ones row-sum; vf read once per (nt,hbl), shared ----
            #pragma unroll
            for (int hbl = 0; hbl < 2; ++hbl) {
                bf16x8 pf[4];
                #pragma unroll
                for (int half = 0; half < 4; ++half) {
                    pf[half] = *(const bf16x8*)(PrB + half * 1024 + hbl * 512);
                    lacc[half] = __builtin_amdgcn_mfma_f32_16x16x32_bf16(
                        pf[half], ones, lacc[half], 0, 0, 0);
                }
                int hb = cc * 2 + hbl;
                #pragma unroll
                for (int nt = 0; nt < 4; ++nt) {
                    bf16x8 vf = *(const bf16x8*)(Vfr + (nt * 4 + hb) * 512);
                    #pragma unroll
                    for (int half = 0; half < 4; ++half)
                        oacc[half][nt] = __builtin_amdgcn_mfma_f32_16x16x32_bf16(
                            pf[half], vf, oacc[half][nt], 0, 0, 0);
                }
            }
        }

        if (t < 15) {
            WAITVM(0);        // K(t+1): issued a full tile of MFMA ago -- free
            PHASE_BARRIER();  // K visible; Vs safe to overwrite next tile
        }
    }

    // ---- normalize + store ----
    #pragma unroll
    for (int half = 0; half < 4; ++half) {
        float il[4];
        #pragma unroll
        for (int r = 0; r < 4; ++r) il[r] = 1.0f / lacc[half][r];
        #pragma unroll
        for (int nt = 0; nt < 4; ++nt) {
            #pragma unroll
            for (int r = 0; r < 4; ++r) {
                size_t orow = (size_t)(b * LQ_ + qt * 256 + w * 64 + half * 16 + quad * 4 + r);
                Out[orow * 1024 + h * 64 + nt * 16 + l15] = oacc[half][nt][r] * il[r];
            }
        }
    }
}

// ---------------------------------------------------------------------------
extern "C" void kernel_launch(void* const* d_in, const int* in_sizes, int n_in,
                              void* d_out, int out_size, void* d_ws, size_t ws_size,
                              hipStream_t stream) {
    const float* zt = (const float*)d_in[0];
    const float* ic = (const float*)d_in[1];
    const float* Wq = (const float*)d_in[2];
    const float* bq = (const float*)d_in[3];
    const float* Wk = (const float*)d_in[4];
    const float* bk = (const float*)d_in[5];
    const float* Wv = (const float*)d_in[6];
    const float* bv = (const float*)d_in[7];
    float* out = (float*)d_out;

    const size_t M8 = (size_t)8192 * 1024;
    const size_t M1 = (size_t)1024 * 1024;
    unsigned short* Qb  = (unsigned short*)d_ws;
    unsigned short* Kb  = Qb  + M8;
    unsigned short* Vtb = Kb  + M8;          // V written transposed by qkv_gemm
    unsigned short* Xz  = Vtb + M8;
    unsigned short* Xi  = Xz  + M8;
    unsigned short* Wqb = Xi  + M8;
    unsigned short* Wkb = Wqb + M1;
    unsigned short* Wvb = Wkb + M1;

    const float qscale = 0.125f * 1.44269504088896f;  // 1/sqrt(64) * log2(e)

    dim3 gcv(4096, 5);
    cvt_all<<<gcv, 256, 0, stream>>>(zt, Xz, ic, Xi,
                                     Wq, Wqb, qscale, Wk, Wkb, Wv, Wvb,
                                     (int)M8, (int)M1);

    dim3 gproj(32, 24);                      // m-tile (8192/256), proj*8 + n-tile
    qkv_gemm<<<gproj, 512, 0, stream>>>(Xz, Xi, Wqb, Wkb, Wvb,
                                        bq, bk, bv, qscale, Qb, Kb, Vtb);

    dim3 gattn(8, 16, 4);                    // flattened+swizzled inside kernel
    attn_kernel<<<gattn, 256, 0, stream>>>(Qb, Kb, Vtb, out);
}

// Round 16
// 273.731 us; speedup vs baseline: 2.9082x; 1.0397x over previous
//
#include <hip/hip_runtime.h>
#include <hip/hip_bf16.h>
#include <cstdint>

#define B_  4
#define LQ_ 2048
#define LK_ 2048
#define D_  1024
#define H_  16
#define HD_ 64

typedef __attribute__((ext_vector_type(8))) short bf16x8;   // 8 bf16 in 4 VGPRs
typedef __attribute__((ext_vector_type(4))) float f32x4;    // MFMA C/D

#if defined(__has_builtin)
#if __has_builtin(__builtin_amdgcn_exp2f)
#define EXP2F(x) __builtin_amdgcn_exp2f(x)
#else
#define EXP2F(x) exp2f(x)
#endif
#else
#define EXP2F(x) exp2f(x)
#endif

__device__ __forceinline__ unsigned short f2b(float f) {   // RNE
    union { float f; unsigned u; } v; v.f = f;
    unsigned u = v.u;
    unsigned r = (u + 0x7fffu + ((u >> 16) & 1u)) >> 16;
    return (unsigned short)r;
}

// async global->LDS, 16B per lane. LDS dest: wave-uniform base + lane*16.
__device__ __forceinline__ void gl_lds16(const unsigned short* g, unsigned short* l) {
    __builtin_amdgcn_global_load_lds(
        (const __attribute__((address_space(1))) unsigned int*)(g),
        (__attribute__((address_space(3))) unsigned int*)(l),
        16, 0, 0);
}

#define PHASE_BARRIER() do { \
    __builtin_amdgcn_sched_barrier(0); \
    __builtin_amdgcn_s_barrier(); \
    __builtin_amdgcn_sched_barrier(0); } while (0)

#define WAITVM(N) do { \
    asm volatile("s_waitcnt vmcnt(" #N ")" ::: "memory"); \
    __builtin_amdgcn_sched_barrier(0); } while (0)

// ---------------------------------------------------------------------------
// Fused fp32->bf16 for all 5 tensors; blockIdx.y selects. Wq scaled by s0.
// ---------------------------------------------------------------------------
__global__ void cvt_all(const float* __restrict__ a0, unsigned short* __restrict__ d0,
                        const float* __restrict__ a1, unsigned short* __restrict__ d1,
                        const float* __restrict__ w0, unsigned short* __restrict__ e0, float s0,
                        const float* __restrict__ w1, unsigned short* __restrict__ e1,
                        const float* __restrict__ w2, unsigned short* __restrict__ e2,
                        int nact, int nw) {
    const float* in; unsigned short* out; float s = 1.0f; int n;
    switch (blockIdx.y) {
        case 0: in = a0; out = d0; n = nact; break;
        case 1: in = a1; out = d1; n = nact; break;
        case 2: in = w0; out = e0; n = nw; s = s0; break;
        case 3: in = w1; out = e1; n = nw; break;
        default: in = w2; out = e2; n = nw; break;
    }
    int i = (blockIdx.x * blockDim.x + threadIdx.x) * 8;
    int stride = gridDim.x * blockDim.x * 8;
    for (; i < n; i += stride) {
        float4 x = *(const float4*)(in + i);
        float4 y = *(const float4*)(in + i + 4);
        bf16x8 v;
        v[0] = (short)f2b(x.x * s); v[1] = (short)f2b(x.y * s);
        v[2] = (short)f2b(x.z * s); v[3] = (short)f2b(x.w * s);
        v[4] = (short)f2b(y.x * s); v[5] = (short)f2b(y.y * s);
        v[6] = (short)f2b(y.z * s); v[7] = (short)f2b(y.w * s);
        *(bf16x8*)(out + i) = v;
    }
}

// ---------------------------------------------------------------------------
// Fused QKV projection GEMM v4 (round-14, measured best) -- 256x128 tile,
// BK as 32 kh-halves, 8 waves (2M x 4N: 8 m-frags x 2 n-frags, acc=64),
// 16 MFMA/phase, grid = 32 x 24 = 768 = 256 CUs x 3 exactly. 4-slot ring
// (96KB), counted-vmcnt ladder (steady vmcnt(6), tail 3->0). V written
// directly transposed.
// ---------------------------------------------------------------------------
__global__ __launch_bounds__(512, 2) void qkv_gemm(
    const unsigned short* __restrict__ Xq,
    const unsigned short* __restrict__ Xkv,
    const unsigned short* __restrict__ Wqb, const unsigned short* __restrict__ Wkb,
    const unsigned short* __restrict__ Wvb,
    const float* __restrict__ bq, const float* __restrict__ bk,
    const float* __restrict__ bv, float qscale,
    unsigned short* __restrict__ Qb, unsigned short* __restrict__ Kb,
    unsigned short* __restrict__ Vtb)
{
    __shared__ unsigned short AS[4][16 * 512];   // slot g&3: 16 A-frags
    __shared__ unsigned short BS[4][8 * 512];    // slot g&3:  8 B-frags

    const int proj = blockIdx.y >> 3;
    const int nt0  = blockIdx.y & 7;
    const unsigned short* X = (proj == 0) ? Xq : Xkv;
    const unsigned short* W = (proj == 0) ? Wqb : (proj == 1 ? Wkb : Wvb);
    const float* bias       = (proj == 0) ? bq  : (proj == 1 ? bk  : bv);
    const float bscale      = (proj == 0) ? qscale : 1.0f;

    const int tid  = threadIdx.x;
    const int lane = tid & 63;
    const int w    = tid >> 6;                 // 0..7
    const int wm   = w & 1, wn = w >> 1;       // 2M x 4N wave grid
    const int m0   = blockIdx.x * 256;
    const int n0   = nt0 * 128;
    const int l15  = lane & 15, quad = lane >> 4;

    f32x4 acc[8][2] = {};

    // staging: wave w owns A-frags w*2, w*2+1 and B-frag w of each slot
    const unsigned short* gA0 = X + (size_t)(m0 + (w * 2) * 16 + l15) * 1024 + quad * 8;
    const unsigned short* gA1 = gA0 + 16 * 1024;
    const unsigned short* gB0 = W + (size_t)(n0 + w * 16 + l15) * 1024 + quad * 8;

#define STAGE(slot, koff) do { \
    gl_lds16(gA0 + (koff), &AS[slot][(w * 2) * 512 + lane * 8]); \
    gl_lds16(gA1 + (koff), &AS[slot][(w * 2 + 1) * 512 + lane * 8]); \
    gl_lds16(gB0 + (koff), &BS[slot][w * 512 + lane * 8]); } while (0)

    const int aoff = (wm * 8) * 512 + lane * 8;   // my 8 m-frags
    const int boff = (wn * 2) * 512 + lane * 8;   // my 2 n-frags

    // prologue: slots 0,1,2 (kh-halves 0,1,2) -> 9 loads in flight
    STAGE(0, 0);
    STAGE(1, 32);
    STAGE(2, 64);

#define QPHASE(slot, WN, do_stage, sslot, skoff) do { \
    WAITVM(WN); \
    PHASE_BARRIER(); \
    bf16x8 af[8], b0, b1; \
    _Pragma("unroll") \
    for (int i = 0; i < 8; ++i) \
        af[i] = *(const bf16x8*)(&AS[slot][aoff + i * 512]); \
    b0 = *(const bf16x8*)(&BS[slot][boff]); \
    b1 = *(const bf16x8*)(&BS[slot][boff + 512]); \
    __builtin_amdgcn_s_setprio(1); \
    _Pragma("unroll") \
    for (int i = 0; i < 8; ++i) { \
        acc[i][0] = __builtin_amdgcn_mfma_f32_16x16x32_bf16(af[i], b0, acc[i][0], 0, 0, 0); \
        acc[i][1] = __builtin_amdgcn_mfma_f32_16x16x32_bf16(af[i], b1, acc[i][1], 0, 0, 0); \
    } \
    __builtin_amdgcn_s_setprio(0); \
    if (do_stage) STAGE(sslot, skoff); } while (0)

    #pragma unroll 2
    for (int t = 0; t < 16; ++t) {
        const int s0 = (2 * t) & 3;          // kh0 slot  (g = 2t)
        const int s1 = (2 * t + 1) & 3;      // kh1 slot  (g = 2t+1)
        const int sa = (2 * t + 3) & 3;      // staged by kh0 phase (g+3)
        const int sb = (2 * t + 4) & 3;      // staged by kh1 phase (g+3)

        if (t < 15) {
            QPHASE(s0, 6, 1, sa, (2 * t + 3) * 32);           // g = 0..28 even
        } else {
            QPHASE(s0, 3, 0, sa, 0);                          // g = 30: no stage
        }
        if (t < 15) {
            QPHASE(s1, 6, (t <= 13), sb, (2 * t + 4) * 32);   // g = 1..29 odd
        } else {
            QPHASE(s1, 0, 0, sb, 0);                          // g = 31: drain
        }
    }

#undef QPHASE
#undef STAGE

    float bvv[2];
    #pragma unroll
    for (int j = 0; j < 2; ++j)
        bvv[j] = bias[n0 + wn * 32 + j * 16 + l15] * bscale;

    if (proj == 2) {
        // ---- transposed epilogue: write Vt[(b*1024+col)*2048 + tok] ----
        #pragma unroll
        for (int i = 0; i < 8; ++i) {
            int row = m0 + wm * 128 + i * 16 + quad * 4;   // token base (r=0..3)
            int bb  = row >> 11;
            int tt  = row & 2047;
            #pragma unroll
            for (int j = 0; j < 2; ++j) {
                int col = n0 + wn * 32 + j * 16 + l15;
                unsigned s0v = f2b(acc[i][j][0] + bvv[j]);
                unsigned s1v = f2b(acc[i][j][1] + bvv[j]);
                unsigned s2v = f2b(acc[i][j][2] + bvv[j]);
                unsigned s3v = f2b(acc[i][j][3] + bvv[j]);
                uint2 pk;
                pk.x = s0v | (s1v << 16);
                pk.y = s2v | (s3v << 16);
                *(uint2*)(Vtb + ((size_t)(bb * 1024 + col)) * 2048 + tt) = pk;
            }
        }
    } else {
        unsigned short* Y = (proj == 0) ? Qb : Kb;
        #pragma unroll
        for (int i = 0; i < 8; ++i) {
            #pragma unroll
            for (int r = 0; r < 4; ++r) {
                int row = m0 + wm * 128 + i * 16 + quad * 4 + r;
                unsigned short* yp = Y + (size_t)row * 1024 + n0 + wn * 32;
                #pragma unroll
                for (int j = 0; j < 2; ++j)
                    yp[j * 16 + l15] = f2b(acc[i][j][r] + bvv[j]);
            }
        }
    }
}

// ---------------------------------------------------------------------------
// Flash attention v8 + T5 setprio: structure identical to the measured-
// correct v8 (shared LDS staging of K and V + XCD swizzle + K double-
// buffer, counted waits, perm-based RHU P-pack). Only change:
// s_setprio(1)/(0) wraps the QK^T and PV MFMA clusters -- the CU scheduler
// favors MFMA-issuing waves while sibling waves run the exp2/pack VALU
// phase (T5: +4-7% on attn, m191; null only in lockstep single-phase
// kernels). No sync or layout changes. LDS: 80KB -> 2 blocks/CU.
// ---------------------------------------------------------------------------
__global__ __launch_bounds__(256, 2) void attn_kernel(
    const unsigned short* __restrict__ Q,
    const unsigned short* __restrict__ Kp,
    const unsigned short* __restrict__ Vt,
    float* __restrict__ Out)
{
    __shared__ unsigned short Ks[2][16 * 512]; // frag f=kt*2+dblk: K[kt*16+l15][dblk*32+quad*8+j]
    __shared__ unsigned short Vs[16 * 512];    // frag f=nt*4+hb:  V^T[nt*16+l15][hb*32+quad*8+j]
    __shared__ unsigned short Ps[4][4096];     // per-wave, per-half 1024: P[16q][64k] frag-ordered

    const int tid  = threadIdx.x;
    const int lane = tid & 63;
    const int w    = tid >> 6;
    const int l15  = lane & 15, quad = lane >> 4;

    // XCD swizzle: all 8 q-tiles of a (b,h) group share bid%8 -> same XCD,
    // K/V stay L2-resident (proven r2: FETCH 141MB -> 25MB).
    const int bid = blockIdx.x + (blockIdx.y << 3) + (blockIdx.z << 7);
    const int glo = bid & 7;
    const int jx  = bid >> 3;          // 0..63
    const int qt  = jx & 7;
    const int g   = glo + ((jx >> 3) << 3);   // 0..63: (b,h) group
    const int h   = g & 15;
    const int b   = g >> 4;

    bf16x8 qf[4][2];
    #pragma unroll
    for (int half = 0; half < 4; ++half) {
        const unsigned short* qptr =
            Q + (size_t)(b * LQ_ + qt * 256 + w * 64 + half * 16 + l15) * 1024 + h * 64;
        qf[half][0] = *(const bf16x8*)(qptr + quad * 8);
        qf[half][1] = *(const bf16x8*)(qptr + 32 + quad * 8);
    }

    bf16x8 ones;
    #pragma unroll
    for (int j = 0; j < 8; ++j) ones[j] = (short)0x3F80;   // bf16 1.0

    f32x4 oacc[4][4] = {};
    f32x4 lacc[4]    = {};

    const unsigned short* Kbase = Kp + (size_t)b * LK_ * 1024 + h * 64;
    const unsigned short* Vbase = Vt + (size_t)(b * 16 + h) * 64 * 2048;

    const unsigned short* gK[4];
    unsigned short* lK[4];                    // buffer-0 LDS dests
    const unsigned short* gV[4];
    unsigned short* lV[4];
    #pragma unroll
    for (int j = 0; j < 4; ++j) {
        int kt = w + (j >> 1) * 4, dblk = j & 1;
        gK[j] = Kbase + (size_t)(kt * 16 + l15) * 1024 + dblk * 32 + quad * 8;
        lK[j] = &Ks[0][(kt * 2 + dblk) * 512 + lane * 8];
        gV[j] = Vbase + (size_t)(w * 16 + l15) * 2048 + j * 32 + quad * 8;
        lV[j] = &Vs[(w * 4 + j) * 512 + lane * 8];
    }

    // P region: element (q,k) at half*1024 + (k>>3)*128 + q*8 + (k&7)
    const int pws = (quad >> 1) * 128 + l15 * 8 + (quad & 1) * 4;
    unsigned short* PwB = &Ps[w][pws];            // + half*1024 + ti*256
    const unsigned short* PrB = &Ps[w][lane * 8]; // + half*1024 + hbl*512
    const unsigned short* KfrB = &Ks[0][lane * 8];
    const unsigned short* Vfr = &Vs[lane * 8];

    // prologue: stage K(0) into buffer 0
    #pragma unroll
    for (int j = 0; j < 4; ++j) gl_lds16(gK[j], lK[j]);

    for (int t = 0; t < 16; ++t) {
        const int cur = t & 1;
        const int k0 = t * 128;

        // stage V(t); prefetch K(t+1) into other buffer
        #pragma unroll
        for (int j = 0; j < 4; ++j) gl_lds16(gV[j] + k0, lV[j]);
        if (t < 15) {
            const int stoff = (cur ^ 1) * 8192;
            #pragma unroll
            for (int j = 0; j < 4; ++j)
                gl_lds16(gK[j] + (size_t)(t + 1) * (128 * 1024), lK[j] + stoff);
        }
        if (t == 0) {          // K(0) landed (V(0)+K(1) = 8 still in flight)
            WAITVM(8);
            PHASE_BARRIER();
        }
        const unsigned short* Kfr = KfrB + cur * 8192;

        #pragma unroll
        for (int cc = 0; cc < 2; ++cc) {          // two 64-key chunks
            // ---- QK^T, all 4 halves share each kf read ----
            f32x4 st[4][4] = {};
            __builtin_amdgcn_s_setprio(1);
            #pragma unroll
            for (int ti = 0; ti < 4; ++ti)
                #pragma unroll
                for (int dblk = 0; dblk < 2; ++dblk) {
                    bf16x8 kf = *(const bf16x8*)(Kfr + ((cc * 4 + ti) * 2 + dblk) * 512);
                    #pragma unroll
                    for (int half = 0; half < 4; ++half)
                        st[half][ti] = __builtin_amdgcn_mfma_f32_16x16x32_bf16(
                            kf, qf[half][dblk], st[half][ti], 0, 0, 0);
                }
            __builtin_amdgcn_s_setprio(0);

            // ---- p = exp2(s); pack (RHU) into per-half P regions ----
            #pragma unroll
            for (int half = 0; half < 4; ++half) {
                unsigned short* pw = PwB + half * 1024;
                #pragma unroll
                for (int ti = 0; ti < 4; ++ti) {
                    unsigned u0 = __float_as_uint(EXP2F(st[half][ti][0])) + 0x8000u;
                    unsigned u1 = __float_as_uint(EXP2F(st[half][ti][1])) + 0x8000u;
                    unsigned u2 = __float_as_uint(EXP2F(st[half][ti][2])) + 0x8000u;
                    unsigned u3 = __float_as_uint(EXP2F(st[half][ti][3])) + 0x8000u;
                    uint2 pk;
                    pk.x = __builtin_amdgcn_perm(u1, u0, 0x07060302);
                    pk.y = __builtin_amdgcn_perm(u3, u2, 0x07060302);
                    *(uint2*)(pw + ti * 256) = pk;
                }
            }

            // ---- after chunk0's compute has covered V latency: V ready ----
            if (cc == 0) {
                if (t < 15) { WAITVM(4); } else { WAITVM(0); }
                PHASE_BARRIER();      // Vs visible to all waves
            }

            // ---- PV + ones row-sum; vf read once per (nt,hbl), shared ----
            #pragma unroll
            for (int hbl = 0; hbl < 2; ++hbl) {
                bf16x8 pf[4];
                __builtin_amdgcn_s_setprio(1);
                #pragma unroll
                for (int half = 0; half < 4; ++half) {
                    pf[half] = *(const bf16x8*)(PrB + half * 1024 + hbl * 512);
                    lacc[half] = __builtin_amdgcn_mfma_f32_16x16x32_bf16(
                        pf[half], ones, lacc[half], 0, 0, 0);
                }
                int hb = cc * 2 + hbl;
                #pragma unroll
                for (int nt = 0; nt < 4; ++nt) {
                    bf16x8 vf = *(const bf16x8*)(Vfr + (nt * 4 + hb) * 512);
                    #pragma unroll
                    for (int half = 0; half < 4; ++half)
                        oacc[half][nt] = __builtin_amdgcn_mfma_f32_16x16x32_bf16(
                            pf[half], vf, oacc[half][nt], 0, 0, 0);
                }
                __builtin_amdgcn_s_setprio(0);
            }
        }

        if (t < 15) {
            WAITVM(0);        // K(t+1): issued a full tile of MFMA ago -- free
            PHASE_BARRIER();  // K visible; Vs safe to overwrite next tile
        }
    }

    // ---- normalize + store ----
    #pragma unroll
    for (int half = 0; half < 4; ++half) {
        float il[4];
        #pragma unroll
        for (int r = 0; r < 4; ++r) il[r] = 1.0f / lacc[half][r];
        #pragma unroll
        for (int nt = 0; nt < 4; ++nt) {
            #pragma unroll
            for (int r = 0; r < 4; ++r) {
                size_t orow = (size_t)(b * LQ_ + qt * 256 + w * 64 + half * 16 + quad * 4 + r);
                Out[orow * 1024 + h * 64 + nt * 16 + l15] = oacc[half][nt][r] * il[r];
            }
        }
    }
}

// ---------------------------------------------------------------------------
extern "C" void kernel_launch(void* const* d_in, const int* in_sizes, int n_in,
                              void* d_out, int out_size, void* d_ws, size_t ws_size,
                              hipStream_t stream) {
    const float* zt = (const float*)d_in[0];
    const float* ic = (const float*)d_in[1];
    const float* Wq = (const float*)d_in[2];
    const float* bq = (const float*)d_in[3];
    const float* Wk = (const float*)d_in[4];
    const float* bk = (const float*)d_in[5];
    const float* Wv = (const float*)d_in[6];
    const float* bv = (const float*)d_in[7];
    float* out = (float*)d_out;

    const size_t M8 = (size_t)8192 * 1024;
    const size_t M1 = (size_t)1024 * 1024;
    unsigned short* Qb  = (unsigned short*)d_ws;
    unsigned short* Kb  = Qb  + M8;
    unsigned short* Vtb = Kb  + M8;          // V written transposed by qkv_gemm
    unsigned short* Xz  = Vtb + M8;
    unsigned short* Xi  = Xz  + M8;
    unsigned short* Wqb = Xi  + M8;
    unsigned short* Wkb = Wqb + M1;
    unsigned short* Wvb = Wkb + M1;

    const float qscale = 0.125f * 1.44269504088896f;  // 1/sqrt(64) * log2(e)

    dim3 gcv(4096, 5);
    cvt_all<<<gcv, 256, 0, stream>>>(zt, Xz, ic, Xi,
                                     Wq, Wqb, qscale, Wk, Wkb, Wv, Wvb,
                                     (int)M8, (int)M1);

    dim3 gproj(32, 24);                      // m-tile (8192/256), proj*8 + n-tile
    qkv_gemm<<<gproj, 512, 0, stream>>>(Xz, Xi, Wqb, Wkb, Wvb,
                                        bq, bk, bv, qscale, Qb, Kb, Vtb);

    dim3 gattn(8, 16, 4);                    // flattened+swizzled inside kernel
    attn_kernel<<<gattn, 256, 0, stream>>>(Qb, Kb, Vtb, out);
}

// Round 17
// 272.826 us; speedup vs baseline: 2.9179x; 1.0033x over previous
//
#include <hip/hip_runtime.h>
#include <hip/hip_bf16.h>
#include <cstdint>

#define B_  4
#define LQ_ 2048
#define LK_ 2048
#define D_  1024
#define H_  16
#define HD_ 64

typedef __attribute__((ext_vector_type(8))) short bf16x8;   // 8 bf16 in 4 VGPRs
typedef __attribute__((ext_vector_type(4))) float f32x4;    // MFMA C/D

#if defined(__has_builtin)
#if __has_builtin(__builtin_amdgcn_exp2f)
#define EXP2F(x) __builtin_amdgcn_exp2f(x)
#else
#define EXP2F(x) exp2f(x)
#endif
#else
#define EXP2F(x) exp2f(x)
#endif

__device__ __forceinline__ unsigned short f2b(float f) {   // RNE
    union { float f; unsigned u; } v; v.f = f;
    unsigned u = v.u;
    unsigned r = (u + 0x7fffu + ((u >> 16) & 1u)) >> 16;
    return (unsigned short)r;
}

// async global->LDS, 16B per lane. LDS dest: wave-uniform base + lane*16.
__device__ __forceinline__ void gl_lds16(const unsigned short* g, unsigned short* l) {
    __builtin_amdgcn_global_load_lds(
        (const __attribute__((address_space(1))) unsigned int*)(g),
        (__attribute__((address_space(3))) unsigned int*)(l),
        16, 0, 0);
}

#define PHASE_BARRIER() do { \
    __builtin_amdgcn_sched_barrier(0); \
    __builtin_amdgcn_s_barrier(); \
    __builtin_amdgcn_sched_barrier(0); } while (0)

#define WAITVM(N) do { \
    asm volatile("s_waitcnt vmcnt(" #N ")" ::: "memory"); \
    __builtin_amdgcn_sched_barrier(0); } while (0)

// ---------------------------------------------------------------------------
// Fused fp32->bf16 for all 5 tensors; blockIdx.y selects. Wq scaled by s0.
// ---------------------------------------------------------------------------
__global__ void cvt_all(const float* __restrict__ a0, unsigned short* __restrict__ d0,
                        const float* __restrict__ a1, unsigned short* __restrict__ d1,
                        const float* __restrict__ w0, unsigned short* __restrict__ e0, float s0,
                        const float* __restrict__ w1, unsigned short* __restrict__ e1,
                        const float* __restrict__ w2, unsigned short* __restrict__ e2,
                        int nact, int nw) {
    const float* in; unsigned short* out; float s = 1.0f; int n;
    switch (blockIdx.y) {
        case 0: in = a0; out = d0; n = nact; break;
        case 1: in = a1; out = d1; n = nact; break;
        case 2: in = w0; out = e0; n = nw; s = s0; break;
        case 3: in = w1; out = e1; n = nw; break;
        default: in = w2; out = e2; n = nw; break;
    }
    int i = (blockIdx.x * blockDim.x + threadIdx.x) * 8;
    int stride = gridDim.x * blockDim.x * 8;
    for (; i < n; i += stride) {
        float4 x = *(const float4*)(in + i);
        float4 y = *(const float4*)(in + i + 4);
        bf16x8 v;
        v[0] = (short)f2b(x.x * s); v[1] = (short)f2b(x.y * s);
        v[2] = (short)f2b(x.z * s); v[3] = (short)f2b(x.w * s);
        v[4] = (short)f2b(y.x * s); v[5] = (short)f2b(y.y * s);
        v[6] = (short)f2b(y.z * s); v[7] = (short)f2b(y.w * s);
        *(bf16x8*)(out + i) = v;
    }
}

// ---------------------------------------------------------------------------
// Fused QKV projection GEMM v5 -- 256x128 tile, BK=64 PER PHASE (32 MFMA
// per barrier, 16 phases; v4 had 16 MFMA / 32 phases -- barrier count
// halved, phase density doubled, per every session datapoint that denser
// phases win). 8 waves (2M x 4N: 8 m-frags x 2 n-frags, acc=64). Grid =
// 32 x 24 = 768 = 256 CUs x 3 exactly (r14 balance win kept).
// 3-slot full-BK ring (48KB/slot -> 144KB LDS of the 160KB pool),
// 6 gl_lds/wave/slot, counted-vmcnt: phase p WAITVM(6) drains slot p%3
// (slot (p+1)%3's 6 stay in flight) -> barrier -> 20 ds_reads -> 2x16
// MFMA (setprio) -> stage slot (p+2)%3. Hazard: phase-p barrier implies
// all waves' slot-(p-1) reads are in regs, so the post-barrier stage of
// (p+2)%3 == (p-1)%3 is safe; writes land 2 phases before their read.
// Tail: p=14 no stage; p=15 WAITVM(0). V written directly transposed.
// ---------------------------------------------------------------------------
__global__ __launch_bounds__(512, 2) void qkv_gemm(
    const unsigned short* __restrict__ Xq,
    const unsigned short* __restrict__ Xkv,
    const unsigned short* __restrict__ Wqb, const unsigned short* __restrict__ Wkb,
    const unsigned short* __restrict__ Wvb,
    const float* __restrict__ bq, const float* __restrict__ bk,
    const float* __restrict__ bv, float qscale,
    unsigned short* __restrict__ Qb, unsigned short* __restrict__ Kb,
    unsigned short* __restrict__ Vtb)
{
    __shared__ unsigned short AS[3][16384];  // slot: kh half hh*8192 + frag*512
    __shared__ unsigned short BS[3][8192];   // slot: hh*4096 + frag*512

    const int proj = blockIdx.y >> 3;
    const int nt0  = blockIdx.y & 7;
    const unsigned short* X = (proj == 0) ? Xq : Xkv;
    const unsigned short* W = (proj == 0) ? Wqb : (proj == 1 ? Wkb : Wvb);
    const float* bias       = (proj == 0) ? bq  : (proj == 1 ? bk  : bv);
    const float bscale      = (proj == 0) ? qscale : 1.0f;

    const int tid  = threadIdx.x;
    const int lane = tid & 63;
    const int w    = tid >> 6;                 // 0..7
    const int wm   = w & 1, wn = w >> 1;       // 2M x 4N wave grid
    const int m0   = blockIdx.x * 256;
    const int n0   = nt0 * 128;
    const int l15  = lane & 15, quad = lane >> 4;

    f32x4 acc[8][2] = {};

    // staging: wave w owns A-frags w*2, w*2+1 and B-frag w (both kh halves)
    const unsigned short* gA0 = X + (size_t)(m0 + (w * 2) * 16 + l15) * 1024 + quad * 8;
    const unsigned short* gA1 = gA0 + 16 * 1024;
    const unsigned short* gB0 = W + (size_t)(n0 + w * 16 + l15) * 1024 + quad * 8;

#define STAGE(slot, koff) do { \
    gl_lds16(gA0 + (koff),      &AS[slot][(w * 2) * 512 + lane * 8]); \
    gl_lds16(gA1 + (koff),      &AS[slot][(w * 2 + 1) * 512 + lane * 8]); \
    gl_lds16(gA0 + (koff) + 32, &AS[slot][8192 + (w * 2) * 512 + lane * 8]); \
    gl_lds16(gA1 + (koff) + 32, &AS[slot][8192 + (w * 2 + 1) * 512 + lane * 8]); \
    gl_lds16(gB0 + (koff),      &BS[slot][w * 512 + lane * 8]); \
    gl_lds16(gB0 + (koff) + 32, &BS[slot][4096 + w * 512 + lane * 8]); } while (0)

    const int aoff = (wm * 8) * 512 + lane * 8;   // my 8 m-frags
    const int boff = (wn * 2) * 512 + lane * 8;   // my 2 n-frags

    // prologue: slots 0,1 (phases 0,1) -> 12 loads in flight
    STAGE(0, 0);
    STAGE(1, 64);

    #pragma unroll
    for (int p = 0; p < 16; ++p) {
        const int sp = p % 3;

        if (p < 15) { WAITVM(6); } else { WAITVM(0); }
        PHASE_BARRIER();

        #pragma unroll
        for (int hh = 0; hh < 2; ++hh) {
            bf16x8 af[8], b0, b1;
            #pragma unroll
            for (int i = 0; i < 8; ++i)
                af[i] = *(const bf16x8*)(&AS[sp][hh * 8192 + aoff + i * 512]);
            b0 = *(const bf16x8*)(&BS[sp][hh * 4096 + boff]);
            b1 = *(const bf16x8*)(&BS[sp][hh * 4096 + boff + 512]);
            __builtin_amdgcn_s_setprio(1);
            #pragma unroll
            for (int i = 0; i < 8; ++i) {
                acc[i][0] = __builtin_amdgcn_mfma_f32_16x16x32_bf16(af[i], b0, acc[i][0], 0, 0, 0);
                acc[i][1] = __builtin_amdgcn_mfma_f32_16x16x32_bf16(af[i], b1, acc[i][1], 0, 0, 0);
            }
            __builtin_amdgcn_s_setprio(0);
        }

        if (p <= 13) STAGE((p + 2) % 3, (p + 2) * 64);
    }

#undef STAGE

    float bvv[2];
    #pragma unroll
    for (int j = 0; j < 2; ++j)
        bvv[j] = bias[n0 + wn * 32 + j * 16 + l15] * bscale;

    if (proj == 2) {
        // ---- transposed epilogue: write Vt[(b*1024+col)*2048 + tok] ----
        #pragma unroll
        for (int i = 0; i < 8; ++i) {
            int row = m0 + wm * 128 + i * 16 + quad * 4;   // token base (r=0..3)
            int bb  = row >> 11;
            int tt  = row & 2047;
            #pragma unroll
            for (int j = 0; j < 2; ++j) {
                int col = n0 + wn * 32 + j * 16 + l15;
                unsigned s0v = f2b(acc[i][j][0] + bvv[j]);
                unsigned s1v = f2b(acc[i][j][1] + bvv[j]);
                unsigned s2v = f2b(acc[i][j][2] + bvv[j]);
                unsigned s3v = f2b(acc[i][j][3] + bvv[j]);
                uint2 pk;
                pk.x = s0v | (s1v << 16);
                pk.y = s2v | (s3v << 16);
                *(uint2*)(Vtb + ((size_t)(bb * 1024 + col)) * 2048 + tt) = pk;
            }
        }
    } else {
        unsigned short* Y = (proj == 0) ? Qb : Kb;
        #pragma unroll
        for (int i = 0; i < 8; ++i) {
            #pragma unroll
            for (int r = 0; r < 4; ++r) {
                int row = m0 + wm * 128 + i * 16 + quad * 4 + r;
                unsigned short* yp = Y + (size_t)row * 1024 + n0 + wn * 32;
                #pragma unroll
                for (int j = 0; j < 2; ++j)
                    yp[j * 16 + l15] = f2b(acc[i][j][r] + bvv[j]);
            }
        }
    }
}

// ---------------------------------------------------------------------------
// Flash attention v8 + T5 setprio (round-16 measured best, ~88us):
// shared LDS staging of K and V + XCD swizzle + K double-buffer, counted
// waits, perm-based RHU P-pack, setprio around QK^T/PV MFMA clusters.
// LDS: 80KB -> 2 blocks/CU. Unchanged this round.
// ---------------------------------------------------------------------------
__global__ __launch_bounds__(256, 2) void attn_kernel(
    const unsigned short* __restrict__ Q,
    const unsigned short* __restrict__ Kp,
    const unsigned short* __restrict__ Vt,
    float* __restrict__ Out)
{
    __shared__ unsigned short Ks[2][16 * 512]; // frag f=kt*2+dblk: K[kt*16+l15][dblk*32+quad*8+j]
    __shared__ unsigned short Vs[16 * 512];    // frag f=nt*4+hb:  V^T[nt*16+l15][hb*32+quad*8+j]
    __shared__ unsigned short Ps[4][4096];     // per-wave, per-half 1024: P[16q][64k] frag-ordered

    const int tid  = threadIdx.x;
    const int lane = tid & 63;
    const int w    = tid >> 6;
    const int l15  = lane & 15, quad = lane >> 4;

    // XCD swizzle: all 8 q-tiles of a (b,h) group share bid%8 -> same XCD,
    // K/V stay L2-resident (proven r2: FETCH 141MB -> 25MB).
    const int bid = blockIdx.x + (blockIdx.y << 3) + (blockIdx.z << 7);
    const int glo = bid & 7;
    const int jx  = bid >> 3;          // 0..63
    const int qt  = jx & 7;
    const int g   = glo + ((jx >> 3) << 3);   // 0..63: (b,h) group
    const int h   = g & 15;
    const int b   = g >> 4;

    bf16x8 qf[4][2];
    #pragma unroll
    for (int half = 0; half < 4; ++half) {
        const unsigned short* qptr =
            Q + (size_t)(b * LQ_ + qt * 256 + w * 64 + half * 16 + l15) * 1024 + h * 64;
        qf[half][0] = *(const bf16x8*)(qptr + quad * 8);
        qf[half][1] = *(const bf16x8*)(qptr + 32 + quad * 8);
    }

    bf16x8 ones;
    #pragma unroll
    for (int j = 0; j < 8; ++j) ones[j] = (short)0x3F80;   // bf16 1.0

    f32x4 oacc[4][4] = {};
    f32x4 lacc[4]    = {};

    const unsigned short* Kbase = Kp + (size_t)b * LK_ * 1024 + h * 64;
    const unsigned short* Vbase = Vt + (size_t)(b * 16 + h) * 64 * 2048;

    const unsigned short* gK[4];
    unsigned short* lK[4];                    // buffer-0 LDS dests
    const unsigned short* gV[4];
    unsigned short* lV[4];
    #pragma unroll
    for (int j = 0; j < 4; ++j) {
        int kt = w + (j >> 1) * 4, dblk = j & 1;
        gK[j] = Kbase + (size_t)(kt * 16 + l15) * 1024 + dblk * 32 + quad * 8;
        lK[j] = &Ks[0][(kt * 2 + dblk) * 512 + lane * 8];
        gV[j] = Vbase + (size_t)(w * 16 + l15) * 2048 + j * 32 + quad * 8;
        lV[j] = &Vs[(w * 4 + j) * 512 + lane * 8];
    }

    // P region: element (q,k) at half*1024 + (k>>3)*128 + q*8 + (k&7)
    const int pws = (quad >> 1) * 128 + l15 * 8 + (quad & 1) * 4;
    unsigned short* PwB = &Ps[w][pws];            // + half*1024 + ti*256
    const unsigned short* PrB = &Ps[w][lane * 8]; // + half*1024 + hbl*512
    const unsigned short* KfrB = &Ks[0][lane * 8];
    const unsigned short* Vfr = &Vs[lane * 8];

    // prologue: stage K(0) into buffer 0
    #pragma unroll
    for (int j = 0; j < 4; ++j) gl_lds16(gK[j], lK[j]);

    for (int t = 0; t < 16; ++t) {
        const int cur = t & 1;
        const int k0 = t * 128;

        // stage V(t); prefetch K(t+1) into other buffer
        #pragma unroll
        for (int j = 0; j < 4; ++j) gl_lds16(gV[j] + k0, lV[j]);
        if (t < 15) {
            const int stoff = (cur ^ 1) * 8192;
            #pragma unroll
            for (int j = 0; j < 4; ++j)
                gl_lds16(gK[j] + (size_t)(t + 1) * (128 * 1024), lK[j] + stoff);
        }
        if (t == 0) {          // K(0) landed (V(0)+K(1) = 8 still in flight)
            WAITVM(8);
            PHASE_BARRIER();
        }
        const unsigned short* Kfr = KfrB + cur * 8192;

        #pragma unroll
        for (int cc = 0; cc < 2; ++cc) {          // two 64-key chunks
            // ---- QK^T, all 4 halves share each kf read ----
            f32x4 st[4][4] = {};
            __builtin_amdgcn_s_setprio(1);
            #pragma unroll
            for (int ti = 0; ti < 4; ++ti)
                #pragma unroll
                for (int dblk = 0; dblk < 2; ++dblk) {
                    bf16x8 kf = *(const bf16x8*)(Kfr + ((cc * 4 + ti) * 2 + dblk) * 512);
                    #pragma unroll
                    for (int half = 0; half < 4; ++half)
                        st[half][ti] = __builtin_amdgcn_mfma_f32_16x16x32_bf16(
                            kf, qf[half][dblk], st[half][ti], 0, 0, 0);
                }
            __builtin_amdgcn_s_setprio(0);

            // ---- p = exp2(s); pack (RHU) into per-half P regions ----
            #pragma unroll
            for (int half = 0; half < 4; ++half) {
                unsigned short* pw = PwB + half * 1024;
                #pragma unroll
                for (int ti = 0; ti < 4; ++ti) {
                    unsigned u0 = __float_as_uint(EXP2F(st[half][ti][0])) + 0x8000u;
                    unsigned u1 = __float_as_uint(EXP2F(st[half][ti][1])) + 0x8000u;
                    unsigned u2 = __float_as_uint(EXP2F(st[half][ti][2])) + 0x8000u;
                    unsigned u3 = __float_as_uint(EXP2F(st[half][ti][3])) + 0x8000u;
                    uint2 pk;
                    pk.x = __builtin_amdgcn_perm(u1, u0, 0x07060302);
                    pk.y = __builtin_amdgcn_perm(u3, u2, 0x07060302);
                    *(uint2*)(pw + ti * 256) = pk;
                }
            }

            // ---- after chunk0's compute has covered V latency: V ready ----
            if (cc == 0) {
                if (t < 15) { WAITVM(4); } else { WAITVM(0); }
                PHASE_BARRIER();      // Vs visible to all waves
            }

            // ---- PV + ones row-sum; vf read once per (nt,hbl), shared ----
            #pragma unroll
            for (int hbl = 0; hbl < 2; ++hbl) {
                bf16x8 pf[4];
                __builtin_amdgcn_s_setprio(1);
                #pragma unroll
                for (int half = 0; half < 4; ++half) {
                    pf[half] = *(const bf16x8*)(PrB + half * 1024 + hbl * 512);
                    lacc[half] = __builtin_amdgcn_mfma_f32_16x16x32_bf16(
                        pf[half], ones, lacc[half], 0, 0, 0);
                }
                int hb = cc * 2 + hbl;
                #pragma unroll
                for (int nt = 0; nt < 4; ++nt) {
                    bf16x8 vf = *(const bf16x8*)(Vfr + (nt * 4 + hb) * 512);
                    #pragma unroll
                    for (int half = 0; half < 4; ++half)
                        oacc[half][nt] = __builtin_amdgcn_mfma_f32_16x16x32_bf16(
                            pf[half], vf, oacc[half][nt], 0, 0, 0);
                }
                __builtin_amdgcn_s_setprio(0);
            }
        }

        if (t < 15) {
            WAITVM(0);        // K(t+1): issued a full tile of MFMA ago -- free
            PHASE_BARRIER();  // K visible; Vs safe to overwrite next tile
        }
    }

    // ---- normalize + store ----
    #pragma unroll
    for (int half = 0; half < 4; ++half) {
        float il[4];
        #pragma unroll
        for (int r = 0; r < 4; ++r) il[r] = 1.0f / lacc[half][r];
        #pragma unroll
        for (int nt = 0; nt < 4; ++nt) {
            #pragma unroll
            for (int r = 0; r < 4; ++r) {
                size_t orow = (size_t)(b * LQ_ + qt * 256 + w * 64 + half * 16 + quad * 4 + r);
                Out[orow * 1024 + h * 64 + nt * 16 + l15] = oacc[half][nt][r] * il[r];
            }
        }
    }
}

// ---------------------------------------------------------------------------
extern "C" void kernel_launch(void* const* d_in, const int* in_sizes, int n_in,
                              void* d_out, int out_size, void* d_ws, size_t ws_size,
                              hipStream_t stream) {
    const float* zt = (const float*)d_in[0];
    const float* ic = (const float*)d_in[1];
    const float* Wq = (const float*)d_in[2];
    const float* bq = (const float*)d_in[3];
    const float* Wk = (const float*)d_in[4];
    const float* bk = (const float*)d_in[5];
    const float* Wv = (const float*)d_in[6];
    const float* bv = (const float*)d_in[7];
    float* out = (float*)d_out;

    const size_t M8 = (size_t)8192 * 1024;
    const size_t M1 = (size_t)1024 * 1024;
    unsigned short* Qb  = (unsigned short*)d_ws;
    unsigned short* Kb  = Qb  + M8;
    unsigned short* Vtb = Kb  + M8;          // V written transposed by qkv_gemm
    unsigned short* Xz  = Vtb + M8;
    unsigned short* Xi  = Xz  + M8;
    unsigned short* Wqb = Xi  + M8;
    unsigned short* Wkb = Wqb + M1;
    unsigned short* Wvb = Wkb + M1;

    const float qscale = 0.125f * 1.44269504088896f;  // 1/sqrt(64) * log2(e)

    dim3 gcv(4096, 5);
    cvt_all<<<gcv, 256, 0, stream>>>(zt, Xz, ic, Xi,
                                     Wq, Wqb, qscale, Wk, Wkb, Wv, Wvb,
                                     (int)M8, (int)M1);

    dim3 gproj(32, 24);                      // m-tile (8192/256), proj*8 + n-tile
    qkv_gemm<<<gproj, 512, 0, stream>>>(Xz, Xi, Wqb, Wkb, Wvb,
                                        bq, bk, bv, qscale, Qb, Kb, Vtb);

    dim3 gattn(8, 16, 4);                    // flattened+swizzled inside kernel
    attn_kernel<<<gattn, 256, 0, stream>>>(Qb, Kb, Vtb, out);
}